// Round 2
// baseline (229.297 us; speedup 1.0000x reference)
//
#include <hip/hip_runtime.h>
#include <stdint.h>
#include <stddef.h>

#define S_LEN 4096
#define EMB   1280
#define NH    16
#define HDIM  80
#define DP    96        // padded head dim for QK^T (3 x K=32)
#define N3    3840
#define QSCALE 0.11180339887498949f   // 1/sqrt(80)
#define LOG2E  1.4426950408889634f

typedef __attribute__((ext_vector_type(4))) float f32x4;
typedef __attribute__((ext_vector_type(4))) short s16x4;
typedef __attribute__((ext_vector_type(8))) short s16x8;
typedef __attribute__((ext_vector_type(8))) __bf16 bf16x8;

typedef __attribute__((address_space(1))) const unsigned int as1_u32;
typedef __attribute__((address_space(3))) unsigned int as3_u32;

__device__ __forceinline__ unsigned short f2bf(float f) {
  union { float f; unsigned int u; } v; v.f = f;
  unsigned int r = v.u + 0x7fffu + ((v.u >> 16) & 1u);
  return (unsigned short)(r >> 16);
}
__device__ __forceinline__ float bf2f(unsigned short b) {
  union { unsigned int u; float f; } v; v.u = ((unsigned int)b) << 16;
  return v.f;
}

__device__ __forceinline__ f32x4 mfma16(s16x8 a, s16x8 b, f32x4 c) {
  return __builtin_amdgcn_mfma_f32_16x16x32_bf16(
      __builtin_bit_cast(bf16x8, a), __builtin_bit_cast(bf16x8, b), c, 0, 0, 0);
}

__device__ __forceinline__ void gload16(const void* g, void* l) {
  __builtin_amdgcn_global_load_lds((as1_u32*)g, (as3_u32*)l, 16, 0, 0);
}

// ---------------- convert f32 -> bf16 (vectorized) ----------------
__global__ __launch_bounds__(256) void cvt_kernel(const float* __restrict__ in,
                                                  unsigned short* __restrict__ out, int n4) {
  int i = blockIdx.x * 256 + threadIdx.x;
  if (i >= n4) return;
  float4 v = ((const float4*)in)[i];
  s16x4 o;
  o[0] = (short)f2bf(v.x); o[1] = (short)f2bf(v.y);
  o[2] = (short)f2bf(v.z); o[3] = (short)f2bf(v.w);
  ((s16x4*)out)[i] = o;
}

// ---------------- cos/sin tables ----------------
__global__ __launch_bounds__(256) void rope_tab_kernel(const float* __restrict__ rope,
                                                       float* __restrict__ cosT,
                                                       float* __restrict__ sinT, int n) {
  int i = blockIdx.x * 256 + threadIdx.x;
  if (i >= n) return;
  float v = rope[i];
  float s, c;
  sincosf(v, &s, &c);
  cosT[i] = c; sinT[i] = s;
}

// ---------------- 128x128 bf16 GEMM, C = A * B^T + bias ----------------
// A: [M][K] bf16, B: [N][K] bf16 (i.e. weight row-major), bias [N] f32
template<int BF16OUT>
__global__ __launch_bounds__(256) void gemm_kernel(const unsigned short* __restrict__ A,
                                                   const unsigned short* __restrict__ B,
                                                   const float* __restrict__ bias,
                                                   void* __restrict__ Cv,
                                                   int M, int N, int K) {
  __shared__ __attribute__((aligned(16))) unsigned short At[128 * 32];
  __shared__ __attribute__((aligned(16))) unsigned short Bt[128 * 32];
  const int t = threadIdx.x;
  const int lane = t & 63, g = lane >> 4, c = lane & 15;
  const int w = t >> 6, wm = w >> 1, wn = w & 1;
  const int m0 = blockIdx.y * 128, n0 = blockIdx.x * 128;

  const unsigned short* ag0 = A + (size_t)(m0 + (t >> 2)) * K + (t & 3) * 8;
  const unsigned short* ag1 = ag0 + (size_t)64 * K;
  const unsigned short* bg0 = B + (size_t)(n0 + (t >> 2)) * K + (t & 3) * 8;
  const unsigned short* bg1 = bg0 + (size_t)64 * K;
  unsigned short* al0 = &At[t * 8];
  unsigned short* al1 = &At[(t + 256) * 8];
  unsigned short* bl0 = &Bt[t * 8];
  unsigned short* bl1 = &Bt[(t + 256) * 8];

  const f32x4 fz = {0.f, 0.f, 0.f, 0.f};
  f32x4 acc[4][4];
#pragma unroll
  for (int i = 0; i < 4; ++i)
#pragma unroll
    for (int j = 0; j < 4; ++j) acc[i][j] = fz;

  for (int k0 = 0; k0 < K; k0 += 32) {
    __syncthreads();
    gload16(ag0 + k0, al0);
    gload16(ag1 + k0, al1);
    gload16(bg0 + k0, bl0);
    gload16(bg1 + k0, bl1);
    __syncthreads();
    s16x8 af[4], bf[4];
#pragma unroll
    for (int mf = 0; mf < 4; ++mf)
      af[mf] = *(const s16x8*)&At[(wm * 64 + mf * 16 + c) * 32 + g * 8];
#pragma unroll
    for (int nf = 0; nf < 4; ++nf)
      bf[nf] = *(const s16x8*)&Bt[(wn * 64 + nf * 16 + c) * 32 + g * 8];
#pragma unroll
    for (int mf = 0; mf < 4; ++mf)
#pragma unroll
      for (int nf = 0; nf < 4; ++nf)
        acc[mf][nf] = mfma16(af[mf], bf[nf], acc[mf][nf]);
  }

  const int crow = m0 + wm * 64 + g * 4;
  const int ccol = n0 + wn * 64 + c;
  float bv[4];
#pragma unroll
  for (int nf = 0; nf < 4; ++nf) bv[nf] = bias[ccol + nf * 16];
#pragma unroll
  for (int mf = 0; mf < 4; ++mf)
#pragma unroll
    for (int r = 0; r < 4; ++r) {
      size_t rowoff = (size_t)(crow + mf * 16 + r) * N;
#pragma unroll
      for (int nf = 0; nf < 4; ++nf) {
        float vo = acc[mf][nf][r] + bv[nf];
        if (BF16OUT)
          ((unsigned short*)Cv)[rowoff + ccol + nf * 16] = f2bf(vo);
        else
          ((float*)Cv)[rowoff + ccol + nf * 16] = vo;
      }
    }
}

// ---------------- RoPE + QKV split + V transpose ----------------
// qkv: [S][3840] bf16 (per row: per head h, [q(80) k(80) v(80)])
// Qb/Kb: [H][S][96] bf16 (Q pre-scaled by 1/sqrt(80), cols 80..96 zero)
// Vt:    [H][80][S] bf16
__global__ __launch_bounds__(256) void rope_split_kernel(const unsigned short* __restrict__ qkv,
                                                         const float* __restrict__ cosT,
                                                         const float* __restrict__ sinT,
                                                         unsigned short* __restrict__ Qb,
                                                         unsigned short* __restrict__ Kb,
                                                         unsigned short* __restrict__ Vt) {
  __shared__ unsigned short vls[80][66];
  const int t = threadIdx.x;
  const int s0 = blockIdx.x * 64, h = blockIdx.y;

  // Part A: rope on q and k, items = 64 rows * 14 j * 2(q/k)
  for (int it = t; it < 64 * 14 * 2; it += 256) {
    int qk = it & 1;
    int jj = (it >> 1) % 14;
    int row = (it >> 1) / 14;
    int s = s0 + row;
    const unsigned short* src = qkv + (size_t)s * N3 + h * 240 + qk * 80;
    unsigned short* dst = (qk ? Kb : Qb) + ((size_t)h * S_LEN + s) * DP;
    if (jj < 10) {
      int d0 = jj * 4;
      s16x4 a = *(const s16x4*)(src + d0);
      s16x4 b = *(const s16x4*)(src + 40 + d0);
      float4 cs = *(const float4*)(cosT + s * 40 + d0);
      float4 sn = *(const float4*)(sinT + s * 40 + d0);
      float sc = qk ? 1.f : QSCALE;
      float ca[4] = {cs.x, cs.y, cs.z, cs.w};
      float sa[4] = {sn.x, sn.y, sn.z, sn.w};
      s16x4 o1, o2;
#pragma unroll
      for (int i = 0; i < 4; ++i) {
        float q1 = bf2f((unsigned short)a[i]);
        float q2 = bf2f((unsigned short)b[i]);
        o1[i] = (short)f2bf((q1 * ca[i] - q2 * sa[i]) * sc);
        o2[i] = (short)f2bf((q2 * ca[i] + q1 * sa[i]) * sc);
      }
      *(s16x4*)(dst + d0) = o1;
      *(s16x4*)(dst + 40 + d0) = o2;
    } else {
      int d0 = 80 + (jj - 10) * 4;
      s16x4 z = {0, 0, 0, 0};
      *(s16x4*)(dst + d0) = z;
    }
  }

  // Part B: V transpose through LDS
  for (int it = t; it < 640; it += 256) {
    int row = it / 10, c8 = it % 10;
    int s = s0 + row;
    s16x8 v = *(const s16x8*)(qkv + (size_t)s * N3 + h * 240 + 160 + c8 * 8);
#pragma unroll
    for (int i = 0; i < 8; ++i) vls[c8 * 8 + i][row] = (unsigned short)v[i];
  }
  __syncthreads();
  for (int it = t; it < 640; it += 256) {
    int d = it / 8, s8 = it % 8;
    s16x8 v;
#pragma unroll
    for (int i = 0; i < 8; ++i) v[i] = (short)vls[d][s8 * 8 + i];
    *(s16x8*)(Vt + ((size_t)h * HDIM + d) * S_LEN + s0 + s8 * 8) = v;
  }
}

// ---------------- flash attention (varlen block-diagonal) ----------------
// Qb/Kb: [H][S][96], Vt: [H][80][S], out ctx: [S][1280] bf16 (col = h*80+d)
__global__ __launch_bounds__(256) void attn_kernel(const unsigned short* __restrict__ Qb,
                                                   const unsigned short* __restrict__ Kb,
                                                   const unsigned short* __restrict__ Vt,
                                                   const int* __restrict__ cu, int ncu,
                                                   unsigned short* __restrict__ ctx) {
  __shared__ __attribute__((aligned(16))) unsigned short Kl[64 * 104];
  __shared__ __attribute__((aligned(16))) unsigned short Vl[80 * 88];
  __shared__ __attribute__((aligned(16))) unsigned short Pl[4][16 * 72];
  const int t = threadIdx.x, lane = t & 63, w = t >> 6, g = lane >> 4, c = lane & 15;
  const int h = blockIdx.y, q0 = blockIdx.x * 64;
  const int nseg = ncu - 1;

  int kb0[4], kb1[4];
#pragma unroll
  for (int r = 0; r < 4; ++r) {
    int s = q0 + w * 16 + g * 4 + r;
    int lo = 0, hi = 0;
    for (int i = 0; i < nseg; ++i) {
      int a = cu[i], b = cu[i + 1];
      if (s >= a && s < b) { lo = a; hi = b; }
    }
    kb0[r] = lo; kb1[r] = hi;
  }
  int ks = 0, ke = 0;
  for (int i = 0; i < nseg; ++i) {
    int a = cu[i], b = cu[i + 1];
    if (q0 >= a && q0 < b) ks = a;
    if (q0 + 63 >= a && q0 + 63 < b) ke = b;
  }

  s16x8 qf[3];
  {
    const unsigned short* qp = Qb + ((size_t)h * S_LEN + q0 + w * 16 + c) * DP + g * 8;
    qf[0] = *(const s16x8*)(qp);
    qf[1] = *(const s16x8*)(qp + 32);
    qf[2] = *(const s16x8*)(qp + 64);
  }

  const f32x4 fz = {0.f, 0.f, 0.f, 0.f};
  float m[4] = {-3e38f, -3e38f, -3e38f, -3e38f};
  float l[4] = {0.f, 0.f, 0.f, 0.f};
  f32x4 o[5];
#pragma unroll
  for (int j = 0; j < 5; ++j) o[j] = fz;

  const unsigned short* kg = Kb + (size_t)h * S_LEN * DP;
  const unsigned short* vg = Vt + (size_t)h * HDIM * S_LEN;

  for (int k0 = ks; k0 < ke; k0 += 64) {
    // reg-stage K and V tiles, then write to LDS after barrier
    s16x8 kreg[3], vreg[3];
#pragma unroll
    for (int i = 0; i < 3; ++i) {
      int ch = t + i * 256;
      kreg[i] = *(const s16x8*)(kg + (size_t)(k0 + ch / 12) * DP + (ch % 12) * 8);
    }
#pragma unroll
    for (int i = 0; i < 3; ++i) {
      int ch = t + i * 256;
      if (ch < 640) vreg[i] = *(const s16x8*)(vg + (size_t)(ch / 8) * S_LEN + k0 + (ch % 8) * 8);
    }
    __syncthreads();
#pragma unroll
    for (int i = 0; i < 3; ++i) {
      int ch = t + i * 256;
      *(s16x8*)&Kl[(ch / 12) * 104 + (ch % 12) * 8] = kreg[i];
    }
#pragma unroll
    for (int i = 0; i < 3; ++i) {
      int ch = t + i * 256;
      if (ch < 640) *(s16x8*)&Vl[(ch / 8) * 88 + (ch % 8) * 8] = vreg[i];
    }
    __syncthreads();

    // QK^T: rows = 16 q rows of this wave, cols = 64 keys
    f32x4 sc[4];
#pragma unroll
    for (int nf = 0; nf < 4; ++nf) sc[nf] = fz;
#pragma unroll
    for (int kk = 0; kk < 3; ++kk)
#pragma unroll
      for (int nf = 0; nf < 4; ++nf) {
        s16x8 kf = *(const s16x8*)&Kl[(nf * 16 + c) * 104 + kk * 32 + g * 8];
        sc[nf] = mfma16(qf[kk], kf, sc[nf]);
      }

    // mask + row max
    float mx[4] = {-3e38f, -3e38f, -3e38f, -3e38f};
#pragma unroll
    for (int nf = 0; nf < 4; ++nf) {
      int tc = k0 + nf * 16 + c;
#pragma unroll
      for (int r = 0; r < 4; ++r) {
        bool ok = (tc >= kb0[r]) && (tc < kb1[r]);
        float sv = ok ? sc[nf][r] : -3e38f;
        sc[nf][r] = sv;
        mx[r] = fmaxf(mx[r], sv);
      }
    }
#pragma unroll
    for (int d = 1; d < 16; d <<= 1)
#pragma unroll
      for (int r = 0; r < 4; ++r) mx[r] = fmaxf(mx[r], __shfl_xor(mx[r], d));

    float f[4], rs[4];
#pragma unroll
    for (int r = 0; r < 4; ++r) {
      float mn = fmaxf(m[r], mx[r]);
      f[r] = exp2f((m[r] - mn) * LOG2E);
      m[r] = mn;
      rs[r] = 0.f;
    }
#pragma unroll
    for (int nf = 0; nf < 4; ++nf) {
#pragma unroll
      for (int r = 0; r < 4; ++r) {
        float p = exp2f((sc[nf][r] - m[r]) * LOG2E);
        rs[r] += p;
        Pl[w][(g * 4 + r) * 72 + nf * 16 + c] = f2bf(p);
      }
    }
#pragma unroll
    for (int d = 1; d < 16; d <<= 1)
#pragma unroll
      for (int r = 0; r < 4; ++r) rs[r] += __shfl_xor(rs[r], d);
#pragma unroll
    for (int r = 0; r < 4; ++r) l[r] = l[r] * f[r] + rs[r];
#pragma unroll
    for (int j = 0; j < 5; ++j)
#pragma unroll
      for (int r = 0; r < 4; ++r) o[j][r] *= f[r];

    // PV
#pragma unroll
    for (int kk = 0; kk < 2; ++kk) {
      s16x8 pf = *(const s16x8*)&Pl[w][c * 72 + kk * 32 + g * 8];
#pragma unroll
      for (int j = 0; j < 5; ++j) {
        s16x8 vf = *(const s16x8*)&Vl[(j * 16 + c) * 88 + kk * 32 + g * 8];
        o[j] = mfma16(pf, vf, o[j]);
      }
    }
  }

  // epilogue
#pragma unroll
  for (int r = 0; r < 4; ++r) {
    float inv = (l[r] > 0.f) ? 1.f / l[r] : 0.f;
    int srow = q0 + w * 16 + g * 4 + r;
#pragma unroll
    for (int j = 0; j < 5; ++j)
      ctx[(size_t)srow * EMB + h * HDIM + j * 16 + c] = f2bf(o[j][r] * inv);
  }
}

// ---------------- launch ----------------
extern "C" void kernel_launch(void* const* d_in, const int* in_sizes, int n_in,
                              void* d_out, int out_size, void* d_ws, size_t ws_size,
                              hipStream_t stream) {
  const float* x      = (const float*)d_in[0];
  const int*   cu     = (const int*)d_in[1];
  const float* rope   = (const float*)d_in[2];
  const float* w_qkv  = (const float*)d_in[3];
  const float* b_qkv  = (const float*)d_in[4];
  const float* w_proj = (const float*)d_in[5];
  const float* b_proj = (const float*)d_in[6];
  float* out = (float*)d_out;
  const int ncu = in_sizes[1];

  char* ws = (char*)d_ws;
  unsigned short* xb     = (unsigned short*)(ws + 0);          // 10485760 B
  unsigned short* wqkvb  = (unsigned short*)(ws + 10485760);   // 9830400 B
  unsigned short* wprojb = (unsigned short*)(ws + 20316160);   // 3276800 B
  float*          cosT   = (float*)(ws + 23592960);            // 655360 B
  float*          sinT   = (float*)(ws + 24248320);            // 655360 B
  unsigned short* qkvb   = (unsigned short*)(ws + 24903680);   // 31457280 B
  unsigned short* Qb     = (unsigned short*)(ws + 56360960);   // 12582912 B
  unsigned short* Kb     = (unsigned short*)(ws + 68943872);   // 12582912 B
  unsigned short* Vt     = (unsigned short*)(ws + 81526784);   // 10485760 B
  unsigned short* ctxb   = (unsigned short*)(ws + 92012544);   // 10485760 B
  // total ws use: 102498304 bytes

  cvt_kernel<<<5120, 256, 0, stream>>>(x, xb, 1310720);
  cvt_kernel<<<4800, 256, 0, stream>>>(w_qkv, wqkvb, 1228800);
  cvt_kernel<<<1600, 256, 0, stream>>>(w_proj, wprojb, 409600);
  rope_tab_kernel<<<640, 256, 0, stream>>>(rope, cosT, sinT, 163840);

  gemm_kernel<1><<<dim3(30, 32), 256, 0, stream>>>(xb, wqkvb, b_qkv, (void*)qkvb,
                                                   4096, 3840, 1280);
  rope_split_kernel<<<dim3(64, 16), 256, 0, stream>>>(qkvb, cosT, sinT, Qb, Kb, Vt);
  attn_kernel<<<dim3(64, 16), 256, 0, stream>>>(Qb, Kb, Vt, cu, ncu, ctxb);
  gemm_kernel<0><<<dim3(10, 32), 256, 0, stream>>>(ctxb, wprojb, b_proj, (void*)out,
                                                   4096, 1280, 1280);
}

// Round 3
// 209.386 us; speedup vs baseline: 1.0951x; 1.0951x over previous
//
#include <hip/hip_runtime.h>
#include <hip/hip_bf16.h>
#include <stdint.h>
#include <stddef.h>

#define S_LEN 4096
#define EMB   1280
#define NH    16
#define HDIM  80
#define DP    96        // padded head dim for QK^T (3 x K=32)
#define N3    3840
#define QSCALE 0.11180339887498949f   // 1/sqrt(80)
#define LOG2E  1.4426950408889634f

typedef __attribute__((ext_vector_type(4))) float f32x4;
typedef __attribute__((ext_vector_type(4))) short s16x4;
typedef __attribute__((ext_vector_type(8))) short s16x8;
typedef __attribute__((ext_vector_type(8))) __bf16 bf16x8;

typedef __attribute__((address_space(1))) const unsigned int as1_u32;
typedef __attribute__((address_space(3))) unsigned int as3_u32;

__device__ __forceinline__ unsigned short f2bf(float f) {
  return __builtin_bit_cast(unsigned short, __float2bfloat16(f));
}
__device__ __forceinline__ float bf2f(unsigned short b) {
  union { unsigned int u; float f; } v; v.u = ((unsigned int)b) << 16;
  return v.f;
}

__device__ __forceinline__ f32x4 mfma16(s16x8 a, s16x8 b, f32x4 c) {
  return __builtin_amdgcn_mfma_f32_16x16x32_bf16(
      __builtin_bit_cast(bf16x8, a), __builtin_bit_cast(bf16x8, b), c, 0, 0, 0);
}

__device__ __forceinline__ void gload16(const void* g, void* l) {
  __builtin_amdgcn_global_load_lds((as1_u32*)g, (as3_u32*)l, 16, 0, 0);
}

// ---------------- convert f32 -> bf16 (vectorized) ----------------
__global__ __launch_bounds__(256) void cvt_kernel(const float* __restrict__ in,
                                                  unsigned short* __restrict__ out, int n4) {
  int i = blockIdx.x * 256 + threadIdx.x;
  if (i >= n4) return;
  float4 v = ((const float4*)in)[i];
  s16x4 o;
  o[0] = (short)f2bf(v.x); o[1] = (short)f2bf(v.y);
  o[2] = (short)f2bf(v.z); o[3] = (short)f2bf(v.w);
  ((s16x4*)out)[i] = o;
}

// ---------------- cos/sin tables ----------------
__global__ __launch_bounds__(256) void rope_tab_kernel(const float* __restrict__ rope,
                                                       float* __restrict__ cosT,
                                                       float* __restrict__ sinT, int n) {
  int i = blockIdx.x * 256 + threadIdx.x;
  if (i >= n) return;
  float v = rope[i];
  float s, c;
  sincosf(v, &s, &c);
  cosT[i] = c; sinT[i] = s;
}

// ---------------- 128x128 bf16 GEMM, C = A * B^T + bias ----------------
template<int BF16OUT>
__global__ __launch_bounds__(256) void gemm_kernel(const unsigned short* __restrict__ A,
                                                   const unsigned short* __restrict__ B,
                                                   const float* __restrict__ bias,
                                                   void* __restrict__ Cv,
                                                   int M, int N, int K) {
  __shared__ __attribute__((aligned(16))) unsigned short At[128 * 32];
  __shared__ __attribute__((aligned(16))) unsigned short Bt[128 * 32];
  const int t = threadIdx.x;
  const int lane = t & 63, g = lane >> 4, c = lane & 15;
  const int w = t >> 6, wm = w >> 1, wn = w & 1;
  const int m0 = blockIdx.y * 128, n0 = blockIdx.x * 128;

  const unsigned short* ag0 = A + (size_t)(m0 + (t >> 2)) * K + (t & 3) * 8;
  const unsigned short* ag1 = ag0 + (size_t)64 * K;
  const unsigned short* bg0 = B + (size_t)(n0 + (t >> 2)) * K + (t & 3) * 8;
  const unsigned short* bg1 = bg0 + (size_t)64 * K;
  unsigned short* al0 = &At[t * 8];
  unsigned short* al1 = &At[(t + 256) * 8];
  unsigned short* bl0 = &Bt[t * 8];
  unsigned short* bl1 = &Bt[(t + 256) * 8];

  const f32x4 fz = {0.f, 0.f, 0.f, 0.f};
  f32x4 acc[4][4];
#pragma unroll
  for (int i = 0; i < 4; ++i)
#pragma unroll
    for (int j = 0; j < 4; ++j) acc[i][j] = fz;

  for (int k0 = 0; k0 < K; k0 += 32) {
    __syncthreads();
    gload16(ag0 + k0, al0);
    gload16(ag1 + k0, al1);
    gload16(bg0 + k0, bl0);
    gload16(bg1 + k0, bl1);
    __syncthreads();
    s16x8 af[4], bf[4];
#pragma unroll
    for (int mf = 0; mf < 4; ++mf)
      af[mf] = *(const s16x8*)&At[(wm * 64 + mf * 16 + c) * 32 + g * 8];
#pragma unroll
    for (int nf = 0; nf < 4; ++nf)
      bf[nf] = *(const s16x8*)&Bt[(wn * 64 + nf * 16 + c) * 32 + g * 8];
#pragma unroll
    for (int mf = 0; mf < 4; ++mf)
#pragma unroll
      for (int nf = 0; nf < 4; ++nf)
        acc[mf][nf] = mfma16(af[mf], bf[nf], acc[mf][nf]);
  }

  const int crow = m0 + wm * 64 + g * 4;
  const int ccol = n0 + wn * 64 + c;
  float bv[4];
#pragma unroll
  for (int nf = 0; nf < 4; ++nf) bv[nf] = bias[ccol + nf * 16];
#pragma unroll
  for (int mf = 0; mf < 4; ++mf)
#pragma unroll
    for (int r = 0; r < 4; ++r) {
      size_t rowoff = (size_t)(crow + mf * 16 + r) * N;
#pragma unroll
      for (int nf = 0; nf < 4; ++nf) {
        float vo = acc[mf][nf][r] + bv[nf];
        if (BF16OUT)
          ((unsigned short*)Cv)[rowoff + ccol + nf * 16] = f2bf(vo);
        else
          ((float*)Cv)[rowoff + ccol + nf * 16] = vo;
      }
    }
}

// ---------------- RoPE + QKV split + V transpose ----------------
// qkv: [S][3840] bf16; Qb/Kb: [H][S][96] bf16 (Q pre-scaled by QSCALE*LOG2E);
// Vt: [H][80][S] bf16
__global__ __launch_bounds__(256) void rope_split_kernel(const unsigned short* __restrict__ qkv,
                                                         const float* __restrict__ cosT,
                                                         const float* __restrict__ sinT,
                                                         unsigned short* __restrict__ Qb,
                                                         unsigned short* __restrict__ Kb,
                                                         unsigned short* __restrict__ Vt) {
  __shared__ unsigned short vls[80][66];
  const int t = threadIdx.x;
  const int s0 = blockIdx.x * 64, h = blockIdx.y;

  for (int it = t; it < 64 * 14 * 2; it += 256) {
    int qk = it & 1;
    int jj = (it >> 1) % 14;
    int row = (it >> 1) / 14;
    int s = s0 + row;
    const unsigned short* src = qkv + (size_t)s * N3 + h * 240 + qk * 80;
    unsigned short* dst = (qk ? Kb : Qb) + ((size_t)h * S_LEN + s) * DP;
    if (jj < 10) {
      int d0 = jj * 4;
      s16x4 a = *(const s16x4*)(src + d0);
      s16x4 b = *(const s16x4*)(src + 40 + d0);
      float4 cs = *(const float4*)(cosT + s * 40 + d0);
      float4 sn = *(const float4*)(sinT + s * 40 + d0);
      float sc = qk ? 1.f : (QSCALE * LOG2E);
      float ca[4] = {cs.x, cs.y, cs.z, cs.w};
      float sa[4] = {sn.x, sn.y, sn.z, sn.w};
      s16x4 o1, o2;
#pragma unroll
      for (int i = 0; i < 4; ++i) {
        float q1 = bf2f((unsigned short)a[i]);
        float q2 = bf2f((unsigned short)b[i]);
        o1[i] = (short)f2bf((q1 * ca[i] - q2 * sa[i]) * sc);
        o2[i] = (short)f2bf((q2 * ca[i] + q1 * sa[i]) * sc);
      }
      *(s16x4*)(dst + d0) = o1;
      *(s16x4*)(dst + 40 + d0) = o2;
    } else {
      int d0 = 80 + (jj - 10) * 4;
      s16x4 z = {0, 0, 0, 0};
      *(s16x4*)(dst + d0) = z;
    }
  }

  for (int it = t; it < 640; it += 256) {
    int row = it / 10, c8 = it % 10;
    int s = s0 + row;
    s16x8 v = *(const s16x8*)(qkv + (size_t)s * N3 + h * 240 + 160 + c8 * 8);
#pragma unroll
    for (int i = 0; i < 8; ++i) vls[c8 * 8 + i][row] = (unsigned short)v[i];
  }
  __syncthreads();
  for (int it = t; it < 640; it += 256) {
    int d = it / 8, s8 = it % 8;
    s16x8 v;
#pragma unroll
    for (int i = 0; i < 8; ++i) v[i] = (short)vls[d][s8 * 8 + i];
    *(s16x8*)(Vt + ((size_t)h * HDIM + d) * S_LEN + s0 + s8 * 8) = v;
  }
}

// ---------------- flash attention (varlen block-diagonal) ----------------
// Qb/Kb: [H][S][96] (Q pre-scaled by QSCALE*LOG2E), Vt: [H][80][S]
// ctx: [S][1280] bf16 (col = h*80+d)
// Vl layout: 96 rows x 64 keys, 16B chunks XOR-swizzled: phys = d*64 + ((kc^(d&7))<<3)
// row 80 of Vl = 1.0 -> o[5] accumulates the softmax denominator (l) for free.
__global__ __launch_bounds__(256, 4) void attn_kernel(const unsigned short* __restrict__ Qb,
                                                      const unsigned short* __restrict__ Kb,
                                                      const unsigned short* __restrict__ Vt,
                                                      const int* __restrict__ cu, int ncu,
                                                      unsigned short* __restrict__ ctx) {
  __shared__ __attribute__((aligned(16))) unsigned short Kl[64 * 104];
  __shared__ __attribute__((aligned(16))) unsigned short Vl[96 * 64];
  __shared__ __attribute__((aligned(16))) unsigned short Pl[4][16 * 72];
  const int t = threadIdx.x, lane = t & 63, w = t >> 6, g = lane >> 4, c = lane & 15;
  const int h = blockIdx.y, q0 = blockIdx.x * 64;
  const int nseg = ncu - 1;

  // segment bounds: per-row (4 rows/lane), per-wave-uniform check, block range
  int kb0[4] = {0, 0, 0, 0}, kb1[4] = {0, 0, 0, 0};
  int wlo = 0, whi = 0, wlo1 = 0, ks = 0, ke = 0;
  const int r0 = q0 + w * 16, r1 = r0 + 15;
  for (int i = 0; i < nseg; ++i) {
    int a = cu[i], b = cu[i + 1];
#pragma unroll
    for (int r = 0; r < 4; ++r) {
      int s = q0 + w * 16 + g * 4 + r;
      if (s >= a && s < b) { kb0[r] = a; kb1[r] = b; }
    }
    if (r0 >= a && r0 < b) { wlo = a; whi = b; }
    if (r1 >= a && r1 < b) { wlo1 = a; }
    if (q0 >= a && q0 < b) ks = a;
    if (q0 + 63 >= a && q0 + 63 < b) ke = b;
  }
  const bool uniform = (wlo == wlo1);
  const int k_begin = ks & ~63;

  // Q fragments (hoisted)
  s16x8 qf[3];
  {
    const unsigned short* qp = Qb + ((size_t)h * S_LEN + q0 + w * 16 + c) * DP + g * 8;
    qf[0] = *(const s16x8*)(qp);
    qf[1] = *(const s16x8*)(qp + 32);
    qf[2] = *(const s16x8*)(qp + 64);
  }

  const unsigned short* kg = Kb + (size_t)h * S_LEN * DP;
  const unsigned short* vg = Vt + (size_t)h * HDIM * S_LEN;

  // staging address precompute (constant across iterations)
  int kA[3], vA[3];
  const unsigned short* kgp[3];
  const unsigned short* vgp[3];
#pragma unroll
  for (int i = 0; i < 3; ++i) {
    int ch = t + i * 256;
    int kr = ch / 12, kc_ = ch % 12;
    kA[i] = kr * 104 + kc_ * 8;
    kgp[i] = kg + (size_t)(k_begin + kr) * DP + kc_ * 8;
    int d = ch >> 3, k8 = ch & 7;
    if (d > 79) d = 79;  // i==2, t>=128: unused, keep addr safe
    vA[i] = d * 64 + ((k8 ^ (d & 7)) << 3);
    vgp[i] = vg + (size_t)d * S_LEN + k_begin + k8 * 8;
  }

  // init Vl rows 80..95: row 80 = 1.0 (denominator trick), 81..95 = 0
  if (t < 128) {
    int d = 80 + (t >> 3), k8 = t & 7;
    unsigned short fv = (d == 80) ? (unsigned short)0x3F80 : (unsigned short)0;
    s16x8 vv;
#pragma unroll
    for (int i = 0; i < 8; ++i) vv[i] = (short)fv;
    *(s16x8*)&Vl[d * 64 + ((k8 ^ (d & 7)) << 3)] = vv;
  }

  const f32x4 fz = {0.f, 0.f, 0.f, 0.f};
  float m[4] = {-1e38f, -1e38f, -1e38f, -1e38f};
  f32x4 o[6];
#pragma unroll
  for (int j = 0; j < 6; ++j) o[j] = fz;

  // prologue: load first tile into regs
  s16x8 kreg[3], vreg[3];
  kreg[0] = *(const s16x8*)kgp[0];
  kreg[1] = *(const s16x8*)kgp[1];
  kreg[2] = *(const s16x8*)kgp[2];
  vreg[0] = *(const s16x8*)vgp[0];
  vreg[1] = *(const s16x8*)vgp[1];
  if (t < 128) vreg[2] = *(const s16x8*)vgp[2];

  for (int k0 = k_begin; k0 < ke; k0 += 64) {
    __syncthreads();  // previous compute done reading LDS
    *(s16x8*)&Kl[kA[0]] = kreg[0];
    *(s16x8*)&Kl[kA[1]] = kreg[1];
    *(s16x8*)&Kl[kA[2]] = kreg[2];
    *(s16x8*)&Vl[vA[0]] = vreg[0];
    *(s16x8*)&Vl[vA[1]] = vreg[1];
    if (t < 128) *(s16x8*)&Vl[vA[2]] = vreg[2];
    if (k0 + 64 < ke) {  // issue next-tile loads; latency hides under compute
#pragma unroll
      for (int i = 0; i < 3; ++i) { kgp[i] += 64 * DP; vgp[i] += 64; }
      kreg[0] = *(const s16x8*)kgp[0];
      kreg[1] = *(const s16x8*)kgp[1];
      kreg[2] = *(const s16x8*)kgp[2];
      vreg[0] = *(const s16x8*)vgp[0];
      vreg[1] = *(const s16x8*)vgp[1];
      if (t < 128) vreg[2] = *(const s16x8*)vgp[2];
    }
    __syncthreads();  // tile ready

    // QK^T (scores already in log2 domain via Q pre-scale)
    f32x4 sc[4];
#pragma unroll
    for (int nf = 0; nf < 4; ++nf) sc[nf] = fz;
#pragma unroll
    for (int kk = 0; kk < 3; ++kk)
#pragma unroll
      for (int nf = 0; nf < 4; ++nf) {
        s16x8 kf = *(const s16x8*)&Kl[(nf * 16 + c) * 104 + kk * 32 + g * 8];
        sc[nf] = mfma16(qf[kk], kf, sc[nf]);
      }

    // mask (skipped on interior tiles) + row max
    float mx[4] = {-1e38f, -1e38f, -1e38f, -1e38f};
    if (uniform && k0 >= wlo && k0 + 64 <= whi) {
#pragma unroll
      for (int nf = 0; nf < 4; ++nf)
#pragma unroll
        for (int r = 0; r < 4; ++r) mx[r] = fmaxf(mx[r], sc[nf][r]);
    } else {
#pragma unroll
      for (int nf = 0; nf < 4; ++nf) {
        int tc = k0 + nf * 16 + c;
#pragma unroll
        for (int r = 0; r < 4; ++r) {
          bool ok = (tc >= kb0[r]) && (tc < kb1[r]);
          float sv = ok ? sc[nf][r] : -3e38f;
          sc[nf][r] = sv;
          mx[r] = fmaxf(mx[r], sv);
        }
      }
    }
#pragma unroll
    for (int d = 1; d < 16; d <<= 1)
#pragma unroll
      for (int r = 0; r < 4; ++r) mx[r] = fmaxf(mx[r], __shfl_xor(mx[r], d));

    float f_[4];
#pragma unroll
    for (int r = 0; r < 4; ++r) {
      float mn = fmaxf(m[r], mx[r]);
      f_[r] = exp2f(m[r] - mn);
      m[r] = mn;
    }
#pragma unroll
    for (int nf = 0; nf < 4; ++nf)
#pragma unroll
      for (int r = 0; r < 4; ++r) {
        float p = exp2f(sc[nf][r] - m[r]);
        Pl[w][(g * 4 + r) * 72 + nf * 16 + c] = f2bf(p);
      }
#pragma unroll
    for (int j = 0; j < 6; ++j)
#pragma unroll
      for (int r = 0; r < 4; ++r) o[j][r] *= f_[r];

    // PV (j=5 row is the ones-row -> denominator)
#pragma unroll
    for (int kk = 0; kk < 2; ++kk) {
      s16x8 pf = *(const s16x8*)&Pl[w][c * 72 + kk * 32 + g * 8];
#pragma unroll
      for (int j = 0; j < 6; ++j) {
        s16x8 vf = *(const s16x8*)&Vl[(j * 16 + c) * 64 + (((kk * 4 + g) ^ (c & 7)) << 3)];
        o[j] = mfma16(pf, vf, o[j]);
      }
    }
  }

  // epilogue: l = o[5] at d-col 80 (held by lanes with c==0 -> shfl from lane g*16)
#pragma unroll
  for (int r = 0; r < 4; ++r) {
    float lsum = __shfl(o[5][r], lane & 48);
    float inv = (lsum > 0.f) ? 1.f / lsum : 0.f;
    int srow = q0 + w * 16 + g * 4 + r;
#pragma unroll
    for (int j = 0; j < 5; ++j)
      ctx[(size_t)srow * EMB + h * HDIM + j * 16 + c] = f2bf(o[j][r] * inv);
  }
}

// ---------------- launch ----------------
extern "C" void kernel_launch(void* const* d_in, const int* in_sizes, int n_in,
                              void* d_out, int out_size, void* d_ws, size_t ws_size,
                              hipStream_t stream) {
  const float* x      = (const float*)d_in[0];
  const int*   cu     = (const int*)d_in[1];
  const float* rope   = (const float*)d_in[2];
  const float* w_qkv  = (const float*)d_in[3];
  const float* b_qkv  = (const float*)d_in[4];
  const float* w_proj = (const float*)d_in[5];
  const float* b_proj = (const float*)d_in[6];
  float* out = (float*)d_out;
  const int ncu = in_sizes[1];

  char* ws = (char*)d_ws;
  unsigned short* xb     = (unsigned short*)(ws + 0);          // 10485760 B
  unsigned short* wqkvb  = (unsigned short*)(ws + 10485760);   // 9830400 B
  unsigned short* wprojb = (unsigned short*)(ws + 20316160);   // 3276800 B
  float*          cosT   = (float*)(ws + 23592960);            // 655360 B
  float*          sinT   = (float*)(ws + 24248320);            // 655360 B
  unsigned short* qkvb   = (unsigned short*)(ws + 24903680);   // 31457280 B
  unsigned short* Qb     = (unsigned short*)(ws + 56360960);   // 12582912 B
  unsigned short* Kb     = (unsigned short*)(ws + 68943872);   // 12582912 B
  unsigned short* Vt     = (unsigned short*)(ws + 81526784);   // 10485760 B
  unsigned short* ctxb   = (unsigned short*)(ws + 92012544);   // 10485760 B

  cvt_kernel<<<5120, 256, 0, stream>>>(x, xb, 1310720);
  cvt_kernel<<<4800, 256, 0, stream>>>(w_qkv, wqkvb, 1228800);
  cvt_kernel<<<1600, 256, 0, stream>>>(w_proj, wprojb, 409600);
  rope_tab_kernel<<<640, 256, 0, stream>>>(rope, cosT, sinT, 163840);

  gemm_kernel<1><<<dim3(30, 32), 256, 0, stream>>>(xb, wqkvb, b_qkv, (void*)qkvb,
                                                   4096, 3840, 1280);
  rope_split_kernel<<<dim3(64, 16), 256, 0, stream>>>(qkvb, cosT, sinT, Qb, Kb, Vt);
  attn_kernel<<<dim3(64, 16), 256, 0, stream>>>(Qb, Kb, Vt, cu, ncu, ctxb);
  gemm_kernel<0><<<dim3(10, 32), 256, 0, stream>>>(ctxb, wprojb, b_proj, (void*)out,
                                                   4096, 1280, 1280);
}

// Round 4
// 189.966 us; speedup vs baseline: 1.2070x; 1.1022x over previous
//
#include <hip/hip_runtime.h>
#include <hip/hip_bf16.h>
#include <stdint.h>
#include <stddef.h>

#define S_LEN 4096
#define EMB   1280
#define NH    16
#define HDIM  80
#define DP    96        // padded head dim for QK^T (3 x K=32)
#define N3    3840
#define QSCALE 0.11180339887498949f   // 1/sqrt(80)
#define LOG2E  1.4426950408889634f

typedef __attribute__((ext_vector_type(4))) float f32x4;
typedef __attribute__((ext_vector_type(4))) short s16x4;
typedef __attribute__((ext_vector_type(8))) short s16x8;
typedef __attribute__((ext_vector_type(8))) __bf16 bf16x8;

typedef __attribute__((address_space(1))) const unsigned int as1_u32;
typedef __attribute__((address_space(3))) unsigned int as3_u32;

__device__ __forceinline__ unsigned short f2bf(float f) {
  return __builtin_bit_cast(unsigned short, __float2bfloat16(f));
}
__device__ __forceinline__ float bf2f(unsigned short b) {
  union { unsigned int u; float f; } v; v.u = ((unsigned int)b) << 16;
  return v.f;
}

__device__ __forceinline__ f32x4 mfma16(s16x8 a, s16x8 b, f32x4 c) {
  return __builtin_amdgcn_mfma_f32_16x16x32_bf16(
      __builtin_bit_cast(bf16x8, a), __builtin_bit_cast(bf16x8, b), c, 0, 0, 0);
}

__device__ __forceinline__ void gload16(const void* g, void* l) {
  __builtin_amdgcn_global_load_lds((as1_u32*)g, (as3_u32*)l, 16, 0, 0);
}

// ---------------- convert f32 -> bf16 (vectorized) ----------------
__global__ __launch_bounds__(256) void cvt_kernel(const float* __restrict__ in,
                                                  unsigned short* __restrict__ out, int n4) {
  int i = blockIdx.x * 256 + threadIdx.x;
  if (i >= n4) return;
  float4 v = ((const float4*)in)[i];
  s16x4 o;
  o[0] = (short)f2bf(v.x); o[1] = (short)f2bf(v.y);
  o[2] = (short)f2bf(v.z); o[3] = (short)f2bf(v.w);
  ((s16x4*)out)[i] = o;
}

// ---------------- cos/sin tables ----------------
__global__ __launch_bounds__(256) void rope_tab_kernel(const float* __restrict__ rope,
                                                       float* __restrict__ cosT,
                                                       float* __restrict__ sinT, int n) {
  int i = blockIdx.x * 256 + threadIdx.x;
  if (i >= n) return;
  float v = rope[i];
  float s, c;
  sincosf(v, &s, &c);
  cosT[i] = c; sinT[i] = s;
}

// ---------------- 256x256 bf16 GEMM (T3/T4-lite), C = A * B^T + bias ----------------
// A: [M][K] bf16, B: [N][K] bf16. 512 threads = 8 waves (2M x 4N).
// BK=32, double-buffered LDS (64 KB), counted vmcnt (never 0 mid-loop),
// XOR chunk swizzle (src-side + read-side; LDS dest linear for global_load_lds).
template<int BF16OUT>
__global__ __launch_bounds__(512, 2) void gemm256_kernel(const unsigned short* __restrict__ A,
                                                         const unsigned short* __restrict__ B,
                                                         const float* __restrict__ bias,
                                                         void* __restrict__ Cv,
                                                         int M, int N, int K) {
  __shared__ __attribute__((aligned(16))) unsigned short lA[2][256 * 32];
  __shared__ __attribute__((aligned(16))) unsigned short lB[2][256 * 32];
  const int t = threadIdx.x;
  const int lane = t & 63, g = lane >> 4, c = lane & 15;
  const int w = t >> 6, wm = w >> 2, wn = w & 3;
  const int m0 = blockIdx.y * 256, n0 = blockIdx.x * 256;
  const int nt = K >> 5;

  // staging: 1024 chunks (16B) per operand tile; 2 chunks/thread/operand.
  // chunk ch -> LDS ushort idx ch*8 (linear); row = ch>>2, slot = ch&3;
  // global col-chunk = slot ^ ((row>>1)&3)  (inverse of read-side swizzle)
  const unsigned short* aSrc[2];
  const unsigned short* bSrc[2];
#pragma unroll
  for (int i = 0; i < 2; ++i) {
    int ch = t + i * 512;
    int row = ch >> 2, slot = ch & 3;
    int qsrc = slot ^ ((row >> 1) & 3);
    aSrc[i] = A + (size_t)(m0 + row) * K + qsrc * 8;
    bSrc[i] = B + (size_t)(n0 + row) * K + qsrc * 8;
  }

#define STAGE256(buf, k0)                                   \
  do {                                                      \
    gload16(aSrc[0] + (k0), &lA[buf][t * 8]);               \
    gload16(aSrc[1] + (k0), &lA[buf][(t + 512) * 8]);       \
    gload16(bSrc[0] + (k0), &lB[buf][t * 8]);               \
    gload16(bSrc[1] + (k0), &lB[buf][(t + 512) * 8]);       \
  } while (0)

  const f32x4 fz = {0.f, 0.f, 0.f, 0.f};
  f32x4 acc[8][4];
#pragma unroll
  for (int i = 0; i < 8; ++i)
#pragma unroll
    for (int j = 0; j < 4; ++j) acc[i][j] = fz;

  // read-side swizzled slot (same for A and B frag rows): q' = g ^ ((c>>1)&3)
  const int qp = g ^ ((c >> 1) & 3);

  STAGE256(0, 0);
  STAGE256(1, 32);

  for (int tt = 0; tt < nt; ++tt) {
    if (tt + 1 < nt) {
      asm volatile("s_waitcnt vmcnt(4)" ::: "memory");
    } else {
      asm volatile("s_waitcnt vmcnt(0)" ::: "memory");
    }
    __builtin_amdgcn_s_barrier();

    const int b = tt & 1;
    s16x8 af[8], bf[4];
#pragma unroll
    for (int mf = 0; mf < 8; ++mf)
      af[mf] = *(const s16x8*)&lA[b][(wm * 128 + mf * 16 + c) * 32 + qp * 8];
#pragma unroll
    for (int nf = 0; nf < 4; ++nf)
      bf[nf] = *(const s16x8*)&lB[b][(wn * 64 + nf * 16 + c) * 32 + qp * 8];

    __builtin_amdgcn_s_setprio(1);
#pragma unroll
    for (int mf = 0; mf < 8; ++mf)
#pragma unroll
      for (int nf = 0; nf < 4; ++nf)
        acc[mf][nf] = mfma16(af[mf], bf[nf], acc[mf][nf]);
    __builtin_amdgcn_s_setprio(0);

    __builtin_amdgcn_s_barrier();
    if (tt + 2 < nt) STAGE256(b, (tt + 2) * 32);
  }
#undef STAGE256

  // epilogue
  const int ccol = n0 + wn * 64 + c;
  float bv[4];
#pragma unroll
  for (int nf = 0; nf < 4; ++nf) bv[nf] = bias[ccol + nf * 16];
#pragma unroll
  for (int mf = 0; mf < 8; ++mf)
#pragma unroll
    for (int r = 0; r < 4; ++r) {
      size_t rowoff = (size_t)(m0 + wm * 128 + mf * 16 + g * 4 + r) * N;
#pragma unroll
      for (int nf = 0; nf < 4; ++nf) {
        float vo = acc[mf][nf][r] + bv[nf];
        if (BF16OUT)
          ((unsigned short*)Cv)[rowoff + ccol + nf * 16] = f2bf(vo);
        else
          ((float*)Cv)[rowoff + ccol + nf * 16] = vo;
      }
    }
}

// ---------------- 128x128 bf16 GEMM, C = A * B^T + bias (kept for proj) ----------------
template<int BF16OUT>
__global__ __launch_bounds__(256) void gemm_kernel(const unsigned short* __restrict__ A,
                                                   const unsigned short* __restrict__ B,
                                                   const float* __restrict__ bias,
                                                   void* __restrict__ Cv,
                                                   int M, int N, int K) {
  __shared__ __attribute__((aligned(16))) unsigned short At[128 * 32];
  __shared__ __attribute__((aligned(16))) unsigned short Bt[128 * 32];
  const int t = threadIdx.x;
  const int lane = t & 63, g = lane >> 4, c = lane & 15;
  const int w = t >> 6, wm = w >> 1, wn = w & 1;
  const int m0 = blockIdx.y * 128, n0 = blockIdx.x * 128;

  const unsigned short* ag0 = A + (size_t)(m0 + (t >> 2)) * K + (t & 3) * 8;
  const unsigned short* ag1 = ag0 + (size_t)64 * K;
  const unsigned short* bg0 = B + (size_t)(n0 + (t >> 2)) * K + (t & 3) * 8;
  const unsigned short* bg1 = bg0 + (size_t)64 * K;
  unsigned short* al0 = &At[t * 8];
  unsigned short* al1 = &At[(t + 256) * 8];
  unsigned short* bl0 = &Bt[t * 8];
  unsigned short* bl1 = &Bt[(t + 256) * 8];

  const f32x4 fz = {0.f, 0.f, 0.f, 0.f};
  f32x4 acc[4][4];
#pragma unroll
  for (int i = 0; i < 4; ++i)
#pragma unroll
    for (int j = 0; j < 4; ++j) acc[i][j] = fz;

  for (int k0 = 0; k0 < K; k0 += 32) {
    __syncthreads();
    gload16(ag0 + k0, al0);
    gload16(ag1 + k0, al1);
    gload16(bg0 + k0, bl0);
    gload16(bg1 + k0, bl1);
    __syncthreads();
    s16x8 af[4], bf[4];
#pragma unroll
    for (int mf = 0; mf < 4; ++mf)
      af[mf] = *(const s16x8*)&At[(wm * 64 + mf * 16 + c) * 32 + g * 8];
#pragma unroll
    for (int nf = 0; nf < 4; ++nf)
      bf[nf] = *(const s16x8*)&Bt[(wn * 64 + nf * 16 + c) * 32 + g * 8];
#pragma unroll
    for (int mf = 0; mf < 4; ++mf)
#pragma unroll
      for (int nf = 0; nf < 4; ++nf)
        acc[mf][nf] = mfma16(af[mf], bf[nf], acc[mf][nf]);
  }

  const int crow = m0 + wm * 64 + g * 4;
  const int ccol = n0 + wn * 64 + c;
  float bv[4];
#pragma unroll
  for (int nf = 0; nf < 4; ++nf) bv[nf] = bias[ccol + nf * 16];
#pragma unroll
  for (int mf = 0; mf < 4; ++mf)
#pragma unroll
    for (int r = 0; r < 4; ++r) {
      size_t rowoff = (size_t)(crow + mf * 16 + r) * N;
#pragma unroll
      for (int nf = 0; nf < 4; ++nf) {
        float vo = acc[mf][nf][r] + bv[nf];
        if (BF16OUT)
          ((unsigned short*)Cv)[rowoff + ccol + nf * 16] = f2bf(vo);
        else
          ((float*)Cv)[rowoff + ccol + nf * 16] = vo;
      }
    }
}

// ---------------- RoPE + QKV split + V transpose ----------------
__global__ __launch_bounds__(256) void rope_split_kernel(const unsigned short* __restrict__ qkv,
                                                         const float* __restrict__ cosT,
                                                         const float* __restrict__ sinT,
                                                         unsigned short* __restrict__ Qb,
                                                         unsigned short* __restrict__ Kb,
                                                         unsigned short* __restrict__ Vt) {
  __shared__ unsigned short vls[80][66];
  const int t = threadIdx.x;
  const int s0 = blockIdx.x * 64, h = blockIdx.y;

  for (int it = t; it < 64 * 14 * 2; it += 256) {
    int qk = it & 1;
    int jj = (it >> 1) % 14;
    int row = (it >> 1) / 14;
    int s = s0 + row;
    const unsigned short* src = qkv + (size_t)s * N3 + h * 240 + qk * 80;
    unsigned short* dst = (qk ? Kb : Qb) + ((size_t)h * S_LEN + s) * DP;
    if (jj < 10) {
      int d0 = jj * 4;
      s16x4 a = *(const s16x4*)(src + d0);
      s16x4 b = *(const s16x4*)(src + 40 + d0);
      float4 cs = *(const float4*)(cosT + s * 40 + d0);
      float4 sn = *(const float4*)(sinT + s * 40 + d0);
      float sc = qk ? 1.f : (QSCALE * LOG2E);
      float ca[4] = {cs.x, cs.y, cs.z, cs.w};
      float sa[4] = {sn.x, sn.y, sn.z, sn.w};
      s16x4 o1, o2;
#pragma unroll
      for (int i = 0; i < 4; ++i) {
        float q1 = bf2f((unsigned short)a[i]);
        float q2 = bf2f((unsigned short)b[i]);
        o1[i] = (short)f2bf((q1 * ca[i] - q2 * sa[i]) * sc);
        o2[i] = (short)f2bf((q2 * ca[i] + q1 * sa[i]) * sc);
      }
      *(s16x4*)(dst + d0) = o1;
      *(s16x4*)(dst + 40 + d0) = o2;
    } else {
      int d0 = 80 + (jj - 10) * 4;
      s16x4 z = {0, 0, 0, 0};
      *(s16x4*)(dst + d0) = z;
    }
  }

  for (int it = t; it < 640; it += 256) {
    int row = it / 10, c8 = it % 10;
    int s = s0 + row;
    s16x8 v = *(const s16x8*)(qkv + (size_t)s * N3 + h * 240 + 160 + c8 * 8);
#pragma unroll
    for (int i = 0; i < 8; ++i) vls[c8 * 8 + i][row] = (unsigned short)v[i];
  }
  __syncthreads();
  for (int it = t; it < 640; it += 256) {
    int d = it / 8, s8 = it % 8;
    s16x8 v;
#pragma unroll
    for (int i = 0; i < 8; ++i) v[i] = (short)vls[d][s8 * 8 + i];
    *(s16x8*)(Vt + ((size_t)h * HDIM + d) * S_LEN + s0 + s8 * 8) = v;
  }
}

// ---------------- flash attention (varlen block-diagonal) ----------------
__global__ __launch_bounds__(256, 4) void attn_kernel(const unsigned short* __restrict__ Qb,
                                                      const unsigned short* __restrict__ Kb,
                                                      const unsigned short* __restrict__ Vt,
                                                      const int* __restrict__ cu, int ncu,
                                                      unsigned short* __restrict__ ctx) {
  __shared__ __attribute__((aligned(16))) unsigned short Kl[64 * 104];
  __shared__ __attribute__((aligned(16))) unsigned short Vl[96 * 64];
  __shared__ __attribute__((aligned(16))) unsigned short Pl[4][16 * 72];
  const int t = threadIdx.x, lane = t & 63, w = t >> 6, g = lane >> 4, c = lane & 15;
  const int h = blockIdx.y, q0 = blockIdx.x * 64;
  const int nseg = ncu - 1;

  int kb0[4] = {0, 0, 0, 0}, kb1[4] = {0, 0, 0, 0};
  int wlo = 0, whi = 0, wlo1 = 0, ks = 0, ke = 0;
  const int r0 = q0 + w * 16, r1 = r0 + 15;
  for (int i = 0; i < nseg; ++i) {
    int a = cu[i], b = cu[i + 1];
#pragma unroll
    for (int r = 0; r < 4; ++r) {
      int s = q0 + w * 16 + g * 4 + r;
      if (s >= a && s < b) { kb0[r] = a; kb1[r] = b; }
    }
    if (r0 >= a && r0 < b) { wlo = a; whi = b; }
    if (r1 >= a && r1 < b) { wlo1 = a; }
    if (q0 >= a && q0 < b) ks = a;
    if (q0 + 63 >= a && q0 + 63 < b) ke = b;
  }
  const bool uniform = (wlo == wlo1);
  const int k_begin = ks & ~63;

  s16x8 qf[3];
  {
    const unsigned short* qp = Qb + ((size_t)h * S_LEN + q0 + w * 16 + c) * DP + g * 8;
    qf[0] = *(const s16x8*)(qp);
    qf[1] = *(const s16x8*)(qp + 32);
    qf[2] = *(const s16x8*)(qp + 64);
  }

  const unsigned short* kg = Kb + (size_t)h * S_LEN * DP;
  const unsigned short* vg = Vt + (size_t)h * HDIM * S_LEN;

  int kA[3], vA[3];
  const unsigned short* kgp[3];
  const unsigned short* vgp[3];
#pragma unroll
  for (int i = 0; i < 3; ++i) {
    int ch = t + i * 256;
    int kr = ch / 12, kc_ = ch % 12;
    kA[i] = kr * 104 + kc_ * 8;
    kgp[i] = kg + (size_t)(k_begin + kr) * DP + kc_ * 8;
    int d = ch >> 3, k8 = ch & 7;
    if (d > 79) d = 79;
    vA[i] = d * 64 + ((k8 ^ (d & 7)) << 3);
    vgp[i] = vg + (size_t)d * S_LEN + k_begin + k8 * 8;
  }

  if (t < 128) {
    int d = 80 + (t >> 3), k8 = t & 7;
    unsigned short fv = (d == 80) ? (unsigned short)0x3F80 : (unsigned short)0;
    s16x8 vv;
#pragma unroll
    for (int i = 0; i < 8; ++i) vv[i] = (short)fv;
    *(s16x8*)&Vl[d * 64 + ((k8 ^ (d & 7)) << 3)] = vv;
  }

  const f32x4 fz = {0.f, 0.f, 0.f, 0.f};
  float m[4] = {-1e38f, -1e38f, -1e38f, -1e38f};
  f32x4 o[6];
#pragma unroll
  for (int j = 0; j < 6; ++j) o[j] = fz;

  s16x8 kreg[3], vreg[3];
  kreg[0] = *(const s16x8*)kgp[0];
  kreg[1] = *(const s16x8*)kgp[1];
  kreg[2] = *(const s16x8*)kgp[2];
  vreg[0] = *(const s16x8*)vgp[0];
  vreg[1] = *(const s16x8*)vgp[1];
  if (t < 128) vreg[2] = *(const s16x8*)vgp[2];

  for (int k0 = k_begin; k0 < ke; k0 += 64) {
    __syncthreads();
    *(s16x8*)&Kl[kA[0]] = kreg[0];
    *(s16x8*)&Kl[kA[1]] = kreg[1];
    *(s16x8*)&Kl[kA[2]] = kreg[2];
    *(s16x8*)&Vl[vA[0]] = vreg[0];
    *(s16x8*)&Vl[vA[1]] = vreg[1];
    if (t < 128) *(s16x8*)&Vl[vA[2]] = vreg[2];
    if (k0 + 64 < ke) {
#pragma unroll
      for (int i = 0; i < 3; ++i) { kgp[i] += 64 * DP; vgp[i] += 64; }
      kreg[0] = *(const s16x8*)kgp[0];
      kreg[1] = *(const s16x8*)kgp[1];
      kreg[2] = *(const s16x8*)kgp[2];
      vreg[0] = *(const s16x8*)vgp[0];
      vreg[1] = *(const s16x8*)vgp[1];
      if (t < 128) vreg[2] = *(const s16x8*)vgp[2];
    }
    __syncthreads();

    f32x4 sc[4];
#pragma unroll
    for (int nf = 0; nf < 4; ++nf) sc[nf] = fz;
#pragma unroll
    for (int kk = 0; kk < 3; ++kk)
#pragma unroll
      for (int nf = 0; nf < 4; ++nf) {
        s16x8 kf = *(const s16x8*)&Kl[(nf * 16 + c) * 104 + kk * 32 + g * 8];
        sc[nf] = mfma16(qf[kk], kf, sc[nf]);
      }

    float mx[4] = {-1e38f, -1e38f, -1e38f, -1e38f};
    if (uniform && k0 >= wlo && k0 + 64 <= whi) {
#pragma unroll
      for (int nf = 0; nf < 4; ++nf)
#pragma unroll
        for (int r = 0; r < 4; ++r) mx[r] = fmaxf(mx[r], sc[nf][r]);
    } else {
#pragma unroll
      for (int nf = 0; nf < 4; ++nf) {
        int tc = k0 + nf * 16 + c;
#pragma unroll
        for (int r = 0; r < 4; ++r) {
          bool ok = (tc >= kb0[r]) && (tc < kb1[r]);
          float sv = ok ? sc[nf][r] : -3e38f;
          sc[nf][r] = sv;
          mx[r] = fmaxf(mx[r], sv);
        }
      }
    }
#pragma unroll
    for (int d = 1; d < 16; d <<= 1)
#pragma unroll
      for (int r = 0; r < 4; ++r) mx[r] = fmaxf(mx[r], __shfl_xor(mx[r], d));

    float f_[4];
#pragma unroll
    for (int r = 0; r < 4; ++r) {
      float mn = fmaxf(m[r], mx[r]);
      f_[r] = exp2f(m[r] - mn);
      m[r] = mn;
    }
#pragma unroll
    for (int nf = 0; nf < 4; ++nf)
#pragma unroll
      for (int r = 0; r < 4; ++r) {
        float p = exp2f(sc[nf][r] - m[r]);
        Pl[w][(g * 4 + r) * 72 + nf * 16 + c] = f2bf(p);
      }
#pragma unroll
    for (int j = 0; j < 6; ++j)
#pragma unroll
      for (int r = 0; r < 4; ++r) o[j][r] *= f_[r];

#pragma unroll
    for (int kk = 0; kk < 2; ++kk) {
      s16x8 pf = *(const s16x8*)&Pl[w][c * 72 + kk * 32 + g * 8];
#pragma unroll
      for (int j = 0; j < 6; ++j) {
        s16x8 vf = *(const s16x8*)&Vl[(j * 16 + c) * 64 + (((kk * 4 + g) ^ (c & 7)) << 3)];
        o[j] = mfma16(pf, vf, o[j]);
      }
    }
  }

#pragma unroll
  for (int r = 0; r < 4; ++r) {
    float lsum = __shfl(o[5][r], lane & 48);
    float inv = (lsum > 0.f) ? 1.f / lsum : 0.f;
    int srow = q0 + w * 16 + g * 4 + r;
#pragma unroll
    for (int j = 0; j < 5; ++j)
      ctx[(size_t)srow * EMB + h * HDIM + j * 16 + c] = f2bf(o[j][r] * inv);
  }
}

// ---------------- launch ----------------
extern "C" void kernel_launch(void* const* d_in, const int* in_sizes, int n_in,
                              void* d_out, int out_size, void* d_ws, size_t ws_size,
                              hipStream_t stream) {
  const float* x      = (const float*)d_in[0];
  const int*   cu     = (const int*)d_in[1];
  const float* rope   = (const float*)d_in[2];
  const float* w_qkv  = (const float*)d_in[3];
  const float* b_qkv  = (const float*)d_in[4];
  const float* w_proj = (const float*)d_in[5];
  const float* b_proj = (const float*)d_in[6];
  float* out = (float*)d_out;
  const int ncu = in_sizes[1];

  char* ws = (char*)d_ws;
  unsigned short* xb     = (unsigned short*)(ws + 0);          // 10485760 B
  unsigned short* wqkvb  = (unsigned short*)(ws + 10485760);   // 9830400 B
  unsigned short* wprojb = (unsigned short*)(ws + 20316160);   // 3276800 B
  float*          cosT   = (float*)(ws + 23592960);            // 655360 B
  float*          sinT   = (float*)(ws + 24248320);            // 655360 B
  unsigned short* qkvb   = (unsigned short*)(ws + 24903680);   // 31457280 B
  unsigned short* Qb     = (unsigned short*)(ws + 56360960);   // 12582912 B
  unsigned short* Kb     = (unsigned short*)(ws + 68943872);   // 12582912 B
  unsigned short* Vt     = (unsigned short*)(ws + 81526784);   // 10485760 B
  unsigned short* ctxb   = (unsigned short*)(ws + 92012544);   // 10485760 B

  cvt_kernel<<<5120, 256, 0, stream>>>(x, xb, 1310720);
  cvt_kernel<<<4800, 256, 0, stream>>>(w_qkv, wqkvb, 1228800);
  cvt_kernel<<<1600, 256, 0, stream>>>(w_proj, wprojb, 409600);
  rope_tab_kernel<<<640, 256, 0, stream>>>(rope, cosT, sinT, 163840);

  gemm256_kernel<1><<<dim3(15, 16), 512, 0, stream>>>(xb, wqkvb, b_qkv, (void*)qkvb,
                                                      4096, 3840, 1280);
  rope_split_kernel<<<dim3(64, 16), 256, 0, stream>>>(qkvb, cosT, sinT, Qb, Kb, Vt);
  attn_kernel<<<dim3(64, 16), 256, 0, stream>>>(Qb, Kb, Vt, cu, ncu, ctxb);
  gemm_kernel<0><<<dim3(10, 32), 256, 0, stream>>>(ctxb, wprojb, b_proj, (void*)out,
                                                   4096, 1280, 1280);
}

// Round 5
// 167.368 us; speedup vs baseline: 1.3700x; 1.1350x over previous
//
#include <hip/hip_runtime.h>
#include <hip/hip_bf16.h>
#include <stdint.h>
#include <stddef.h>

#define S_LEN 4096
#define EMB   1280
#define NH    16
#define HDIM  80
#define N3    3840
#define QSCALE 0.11180339887498949f   // 1/sqrt(80)
#define LOG2E  1.4426950408889634f

typedef __attribute__((ext_vector_type(4))) float f32x4;
typedef __attribute__((ext_vector_type(16))) float f32x16;
typedef __attribute__((ext_vector_type(4))) short s16x4;
typedef __attribute__((ext_vector_type(8))) short s16x8;
typedef __attribute__((ext_vector_type(8))) __bf16 bf16x8;

typedef __attribute__((address_space(1))) const unsigned int as1_u32;
typedef __attribute__((address_space(3))) unsigned int as3_u32;

__device__ __forceinline__ unsigned short f2bf(float f) {
  return __builtin_bit_cast(unsigned short, __float2bfloat16(f));
}
__device__ __forceinline__ float bf2f(unsigned short b) {
  union { unsigned int u; float f; } v; v.u = ((unsigned int)b) << 16;
  return v.f;
}

__device__ __forceinline__ f32x4 mfma16(s16x8 a, s16x8 b, f32x4 c) {
  return __builtin_amdgcn_mfma_f32_16x16x32_bf16(
      __builtin_bit_cast(bf16x8, a), __builtin_bit_cast(bf16x8, b), c, 0, 0, 0);
}
__device__ __forceinline__ f32x16 mfma32(s16x8 a, s16x8 b, f32x16 c) {
  return __builtin_amdgcn_mfma_f32_32x32x16_bf16(
      __builtin_bit_cast(bf16x8, a), __builtin_bit_cast(bf16x8, b), c, 0, 0, 0);
}

__device__ __forceinline__ unsigned cvtpk_bf16(float a, float b) {
  unsigned r;
  asm("v_cvt_pk_bf16_f32 %0, %1, %2" : "=v"(r) : "v"(a), "v"(b));
  return r;
}

__device__ __forceinline__ void gload16(const void* g, void* l) {
  __builtin_amdgcn_global_load_lds((as1_u32*)g, (as3_u32*)l, 16, 0, 0);
}

// ---------------- convert f32 -> bf16 (vectorized) ----------------
__global__ __launch_bounds__(256) void cvt_kernel(const float* __restrict__ in,
                                                  unsigned short* __restrict__ out, int n4) {
  int i = blockIdx.x * 256 + threadIdx.x;
  if (i >= n4) return;
  float4 v = ((const float4*)in)[i];
  s16x4 o;
  o[0] = (short)f2bf(v.x); o[1] = (short)f2bf(v.y);
  o[2] = (short)f2bf(v.z); o[3] = (short)f2bf(v.w);
  ((s16x4*)out)[i] = o;
}

// ---------------- cos/sin tables ----------------
__global__ __launch_bounds__(256) void rope_tab_kernel(const float* __restrict__ rope,
                                                       float* __restrict__ cosT,
                                                       float* __restrict__ sinT, int n) {
  int i = blockIdx.x * 256 + threadIdx.x;
  if (i >= n) return;
  float v = rope[i];
  float s, c;
  sincosf(v, &s, &c);
  cosT[i] = c; sinT[i] = s;
}

// ---------------- 256x256 bf16 GEMM (T3/T4-lite), C = A * B^T + bias ----------------
template<int BF16OUT>
__global__ __launch_bounds__(512, 2) void gemm256_kernel(const unsigned short* __restrict__ A,
                                                         const unsigned short* __restrict__ B,
                                                         const float* __restrict__ bias,
                                                         void* __restrict__ Cv,
                                                         int M, int N, int K) {
  __shared__ __attribute__((aligned(16))) unsigned short lA[2][256 * 32];
  __shared__ __attribute__((aligned(16))) unsigned short lB[2][256 * 32];
  const int t = threadIdx.x;
  const int lane = t & 63, g = lane >> 4, c = lane & 15;
  const int w = t >> 6, wm = w >> 2, wn = w & 3;
  const int m0 = blockIdx.y * 256, n0 = blockIdx.x * 256;
  const int nt = K >> 5;

  const unsigned short* aSrc[2];
  const unsigned short* bSrc[2];
#pragma unroll
  for (int i = 0; i < 2; ++i) {
    int ch = t + i * 512;
    int row = ch >> 2, slot = ch & 3;
    int qsrc = slot ^ ((row >> 1) & 3);
    aSrc[i] = A + (size_t)(m0 + row) * K + qsrc * 8;
    bSrc[i] = B + (size_t)(n0 + row) * K + qsrc * 8;
  }

#define STAGE256(buf, k0)                                   \
  do {                                                      \
    gload16(aSrc[0] + (k0), &lA[buf][t * 8]);               \
    gload16(aSrc[1] + (k0), &lA[buf][(t + 512) * 8]);       \
    gload16(bSrc[0] + (k0), &lB[buf][t * 8]);               \
    gload16(bSrc[1] + (k0), &lB[buf][(t + 512) * 8]);       \
  } while (0)

  const f32x4 fz = {0.f, 0.f, 0.f, 0.f};
  f32x4 acc[8][4];
#pragma unroll
  for (int i = 0; i < 8; ++i)
#pragma unroll
    for (int j = 0; j < 4; ++j) acc[i][j] = fz;

  const int qp = g ^ ((c >> 1) & 3);

  STAGE256(0, 0);
  STAGE256(1, 32);

  for (int tt = 0; tt < nt; ++tt) {
    if (tt + 1 < nt) {
      asm volatile("s_waitcnt vmcnt(4)" ::: "memory");
    } else {
      asm volatile("s_waitcnt vmcnt(0)" ::: "memory");
    }
    __builtin_amdgcn_s_barrier();

    const int b = tt & 1;
    s16x8 af[8], bf[4];
#pragma unroll
    for (int mf = 0; mf < 8; ++mf)
      af[mf] = *(const s16x8*)&lA[b][(wm * 128 + mf * 16 + c) * 32 + qp * 8];
#pragma unroll
    for (int nf = 0; nf < 4; ++nf)
      bf[nf] = *(const s16x8*)&lB[b][(wn * 64 + nf * 16 + c) * 32 + qp * 8];

    __builtin_amdgcn_s_setprio(1);
#pragma unroll
    for (int mf = 0; mf < 8; ++mf)
#pragma unroll
      for (int nf = 0; nf < 4; ++nf)
        acc[mf][nf] = mfma16(af[mf], bf[nf], acc[mf][nf]);
    __builtin_amdgcn_s_setprio(0);

    __builtin_amdgcn_s_barrier();
    if (tt + 2 < nt) STAGE256(b, (tt + 2) * 32);
  }
#undef STAGE256

  const int ccol = n0 + wn * 64 + c;
  float bv[4];
#pragma unroll
  for (int nf = 0; nf < 4; ++nf) bv[nf] = bias[ccol + nf * 16];
#pragma unroll
  for (int mf = 0; mf < 8; ++mf)
#pragma unroll
    for (int r = 0; r < 4; ++r) {
      size_t rowoff = (size_t)(m0 + wm * 128 + mf * 16 + g * 4 + r) * N;
#pragma unroll
      for (int nf = 0; nf < 4; ++nf) {
        float vo = acc[mf][nf][r] + bv[nf];
        if (BF16OUT)
          ((unsigned short*)Cv)[rowoff + ccol + nf * 16] = f2bf(vo);
        else
          ((float*)Cv)[rowoff + ccol + nf * 16] = vo;
      }
    }
}

// ---------------- 128x128 bf16 GEMM (proj) ----------------
template<int BF16OUT>
__global__ __launch_bounds__(256) void gemm_kernel(const unsigned short* __restrict__ A,
                                                   const unsigned short* __restrict__ B,
                                                   const float* __restrict__ bias,
                                                   void* __restrict__ Cv,
                                                   int M, int N, int K) {
  __shared__ __attribute__((aligned(16))) unsigned short At[128 * 32];
  __shared__ __attribute__((aligned(16))) unsigned short Bt[128 * 32];
  const int t = threadIdx.x;
  const int lane = t & 63, g = lane >> 4, c = lane & 15;
  const int w = t >> 6, wm = w >> 1, wn = w & 1;
  const int m0 = blockIdx.y * 128, n0 = blockIdx.x * 128;

  const unsigned short* ag0 = A + (size_t)(m0 + (t >> 2)) * K + (t & 3) * 8;
  const unsigned short* ag1 = ag0 + (size_t)64 * K;
  const unsigned short* bg0 = B + (size_t)(n0 + (t >> 2)) * K + (t & 3) * 8;
  const unsigned short* bg1 = bg0 + (size_t)64 * K;
  unsigned short* al0 = &At[t * 8];
  unsigned short* al1 = &At[(t + 256) * 8];
  unsigned short* bl0 = &Bt[t * 8];
  unsigned short* bl1 = &Bt[(t + 256) * 8];

  const f32x4 fz = {0.f, 0.f, 0.f, 0.f};
  f32x4 acc[4][4];
#pragma unroll
  for (int i = 0; i < 4; ++i)
#pragma unroll
    for (int j = 0; j < 4; ++j) acc[i][j] = fz;

  for (int k0 = 0; k0 < K; k0 += 32) {
    __syncthreads();
    gload16(ag0 + k0, al0);
    gload16(ag1 + k0, al1);
    gload16(bg0 + k0, bl0);
    gload16(bg1 + k0, bl1);
    __syncthreads();
    s16x8 af[4], bf[4];
#pragma unroll
    for (int mf = 0; mf < 4; ++mf)
      af[mf] = *(const s16x8*)&At[(wm * 64 + mf * 16 + c) * 32 + g * 8];
#pragma unroll
    for (int nf = 0; nf < 4; ++nf)
      bf[nf] = *(const s16x8*)&Bt[(wn * 64 + nf * 16 + c) * 32 + g * 8];
#pragma unroll
    for (int mf = 0; mf < 4; ++mf)
#pragma unroll
      for (int nf = 0; nf < 4; ++nf)
        acc[mf][nf] = mfma16(af[mf], bf[nf], acc[mf][nf]);
  }

  const int crow = m0 + wm * 64 + g * 4;
  const int ccol = n0 + wn * 64 + c;
  float bv[4];
#pragma unroll
  for (int nf = 0; nf < 4; ++nf) bv[nf] = bias[ccol + nf * 16];
#pragma unroll
  for (int mf = 0; mf < 4; ++mf)
#pragma unroll
    for (int r = 0; r < 4; ++r) {
      size_t rowoff = (size_t)(crow + mf * 16 + r) * N;
#pragma unroll
      for (int nf = 0; nf < 4; ++nf) {
        float vo = acc[mf][nf][r] + bv[nf];
        if (BF16OUT)
          ((unsigned short*)Cv)[rowoff + ccol + nf * 16] = f2bf(vo);
        else
          ((float*)Cv)[rowoff + ccol + nf * 16] = vo;
      }
    }
}

// ---------------- RoPE + QKV split + V transpose ----------------
// qkv: [S][3840] bf16; Qb/Kb: [H][S][80] bf16 (Q pre-scaled by QSCALE*LOG2E);
// Vt: [H][80][S] bf16
__global__ __launch_bounds__(256) void rope_split_kernel(const unsigned short* __restrict__ qkv,
                                                         const float* __restrict__ cosT,
                                                         const float* __restrict__ sinT,
                                                         unsigned short* __restrict__ Qb,
                                                         unsigned short* __restrict__ Kb,
                                                         unsigned short* __restrict__ Vt) {
  __shared__ unsigned short vls[80][66];
  const int t = threadIdx.x;
  const int s0 = blockIdx.x * 64, h = blockIdx.y;

  for (int it = t; it < 64 * 10 * 2; it += 256) {
    int qk = it & 1;
    int jj = (it >> 1) % 10;
    int row = (it >> 1) / 10;
    int s = s0 + row;
    const unsigned short* src = qkv + (size_t)s * N3 + h * 240 + qk * 80;
    unsigned short* dst = (qk ? Kb : Qb) + ((size_t)h * S_LEN + s) * HDIM;
    int d0 = jj * 4;
    s16x4 a = *(const s16x4*)(src + d0);
    s16x4 b = *(const s16x4*)(src + 40 + d0);
    float4 cs = *(const float4*)(cosT + s * 40 + d0);
    float4 sn = *(const float4*)(sinT + s * 40 + d0);
    float sc = qk ? 1.f : (QSCALE * LOG2E);
    float ca[4] = {cs.x, cs.y, cs.z, cs.w};
    float sa[4] = {sn.x, sn.y, sn.z, sn.w};
    s16x4 o1, o2;
#pragma unroll
    for (int i = 0; i < 4; ++i) {
      float q1 = bf2f((unsigned short)a[i]);
      float q2 = bf2f((unsigned short)b[i]);
      o1[i] = (short)f2bf((q1 * ca[i] - q2 * sa[i]) * sc);
      o2[i] = (short)f2bf((q2 * ca[i] + q1 * sa[i]) * sc);
    }
    *(s16x4*)(dst + d0) = o1;
    *(s16x4*)(dst + 40 + d0) = o2;
  }

  for (int it = t; it < 640; it += 256) {
    int row = it / 10, c8 = it % 10;
    int s = s0 + row;
    s16x8 v = *(const s16x8*)(qkv + (size_t)s * N3 + h * 240 + 160 + c8 * 8);
#pragma unroll
    for (int i = 0; i < 8; ++i) vls[c8 * 8 + i][row] = (unsigned short)v[i];
  }
  __syncthreads();
  for (int it = t; it < 640; it += 256) {
    int d = it / 8, s8 = it % 8;
    s16x8 v;
#pragma unroll
    for (int i = 0; i < 8; ++i) v[i] = (short)vls[d][s8 * 8 + i];
    *(s16x8*)(Vt + ((size_t)h * HDIM + d) * S_LEN + s0 + s8 * 8) = v;
  }
}

// ---------------- flash attention, 32x32 swapped-QK^T, P-in-register ----------------
// Qb/Kb: [H][S][80] (Q pre-scaled by QSCALE*LOG2E), Vt: [H][80][S]
// ctx: [S][1280] bf16 (col = h*80+d). Block = 4 waves x 32 q-rows = 128 rows.
// Kl: [64 keys][256B] chunk-swizzled; Vl: [96 d][256B] (row 80 = ones -> l-sum).
__global__ __launch_bounds__(256, 2) void attn_kernel(const unsigned short* __restrict__ Qb,
                                                      const unsigned short* __restrict__ Kb,
                                                      const unsigned short* __restrict__ Vt,
                                                      const int* __restrict__ cu, int ncu,
                                                      unsigned short* __restrict__ ctx) {
  __shared__ __attribute__((aligned(16))) unsigned short Kl[64 * 128];
  __shared__ __attribute__((aligned(16))) unsigned short Vl[96 * 128];
  const int t = threadIdx.x, lane = t & 63, w = t >> 6;
  const int cq = lane & 31, hi = lane >> 5;
  const int h = blockIdx.y, q0 = blockIdx.x * 128;
  const int nseg = ncu - 1;

  // segment bounds
  int qlo = 0, qhi = 0, ks = 0, ke = 0, wlo = 0, whi = 0, wlo2 = 0;
  const int myq = q0 + w * 32 + cq;
  const int wr0 = q0 + w * 32, wr1 = wr0 + 31;
  for (int i = 0; i < nseg; ++i) {
    int a = cu[i], b = cu[i + 1];
    if (myq >= a && myq < b) { qlo = a; qhi = b; }
    if (wr0 >= a && wr0 < b) { wlo = a; whi = b; }
    if (wr1 >= a && wr1 < b) { wlo2 = a; }
    if (q0 >= a && q0 < b) ks = a;
    if (q0 + 127 >= a && q0 + 127 < b) ke = b;
  }
  const bool uniform = (wlo == wlo2);
  const int k_begin = ks & ~63;

  // Q fragments: lane holds Q[q=cq][k = kk*16 + hi*8 + j]
  s16x8 qf[5];
  {
    const unsigned short* qp = Qb + ((size_t)h * S_LEN + q0 + w * 32 + cq) * HDIM + hi * 8;
#pragma unroll
    for (int kk = 0; kk < 5; ++kk) qf[kk] = *(const s16x8*)(qp + kk * 16);
  }

  const unsigned short* kg = Kb + (size_t)h * S_LEN * HDIM;
  const unsigned short* vg = Vt + (size_t)h * HDIM * S_LEN;

  // staging maps (hoisted): K 640 chunks (row=ch&63, kc=ch>>6), V 640 (d=ch%80, vk=ch/80)
  int kA[3], vA[3];
  const unsigned short* kgp[3];
  const unsigned short* vgp[3];
#pragma unroll
  for (int i = 0; i < 3; ++i) {
    int ch = t + i * 256;
    int chk = (ch < 640) ? ch : 0;
    int kr = chk & 63, kc = chk >> 6;
    kA[i] = kr * 128 + ((kc ^ (kr & 15)) << 3);
    kgp[i] = kg + (size_t)(k_begin + kr) * HDIM + kc * 8;
    int vd = chk % 80, vk = chk / 80;
    vA[i] = vd * 128 + ((vk ^ (vd & 15)) << 3);
    vgp[i] = vg + (size_t)vd * S_LEN + k_begin + vk * 8;
  }

  // init Vl rows 80..95: row 80 = 1.0 (denominator), rest 0
  if (t < 128) {
    int d = 80 + (t >> 3), c8 = t & 7;
    unsigned short fv = (d == 80) ? (unsigned short)0x3F80 : (unsigned short)0;
    s16x8 vv;
#pragma unroll
    for (int i = 0; i < 8; ++i) vv[i] = (short)fv;
    *(s16x8*)&Vl[d * 128 + ((c8 ^ (d & 15)) << 3)] = vv;
  }

  const f32x16 z16 = {0.f,0.f,0.f,0.f,0.f,0.f,0.f,0.f,0.f,0.f,0.f,0.f,0.f,0.f,0.f,0.f};
  f32x16 o0 = z16, o1 = z16, o2 = z16;
  float m = -1e38f;

  // prologue loads
  s16x8 kreg[3], vreg[3];
  kreg[0] = *(const s16x8*)kgp[0];
  kreg[1] = *(const s16x8*)kgp[1];
  vreg[0] = *(const s16x8*)vgp[0];
  vreg[1] = *(const s16x8*)vgp[1];
  if (t < 128) { kreg[2] = *(const s16x8*)kgp[2]; vreg[2] = *(const s16x8*)vgp[2]; }

  for (int k0 = k_begin; k0 < ke; k0 += 64) {
    __syncthreads();
    *(s16x8*)&Kl[kA[0]] = kreg[0];
    *(s16x8*)&Kl[kA[1]] = kreg[1];
    *(s16x8*)&Vl[vA[0]] = vreg[0];
    *(s16x8*)&Vl[vA[1]] = vreg[1];
    if (t < 128) { *(s16x8*)&Kl[kA[2]] = kreg[2]; *(s16x8*)&Vl[vA[2]] = vreg[2]; }
    if (k0 + 64 < ke) {
#pragma unroll
      for (int i = 0; i < 3; ++i) { kgp[i] += 64 * HDIM; vgp[i] += 64; }
      kreg[0] = *(const s16x8*)kgp[0];
      kreg[1] = *(const s16x8*)kgp[1];
      vreg[0] = *(const s16x8*)vgp[0];
      vreg[1] = *(const s16x8*)vgp[1];
      if (t < 128) { kreg[2] = *(const s16x8*)kgp[2]; vreg[2] = *(const s16x8*)vgp[2]; }
    }
    __syncthreads();

    // QK^T swapped: C[key][q] ; lane holds q=cq, keys (r&3)+8*(r>>2)+4*hi (+nf*32)
    f32x16 sc0 = z16, sc1 = z16;
#pragma unroll
    for (int kk = 0; kk < 5; ++kk) {
      const int cb = ((2 * kk + hi) ^ (cq & 15)) << 3;
      s16x8 kf0 = *(const s16x8*)&Kl[cq * 128 + cb];
      s16x8 kf1 = *(const s16x8*)&Kl[(32 + cq) * 128 + cb];
      sc0 = mfma32(kf0, qf[kk], sc0);
      sc1 = mfma32(kf1, qf[kk], sc1);
    }

    // mask (boundary tiles only)
    if (!(uniform && k0 >= wlo && k0 + 64 <= whi)) {
#pragma unroll
      for (int r = 0; r < 16; ++r) {
        int key0 = k0 + (r & 3) + 8 * (r >> 2) + 4 * hi;
        int key1 = key0 + 32;
        sc0[r] = (key0 >= qlo && key0 < qhi) ? sc0[r] : -3e38f;
        sc1[r] = (key1 >= qlo && key1 < qhi) ? sc1[r] : -3e38f;
      }
    }

    // per-q-row max (in-lane 32 + cross-half)
    float pm = fmaxf(sc0[0], sc1[0]);
#pragma unroll
    for (int r = 1; r < 16; ++r) pm = fmaxf(pm, fmaxf(sc0[r], sc1[r]));
    pm = fmaxf(pm, __shfl_xor(pm, 32));

    // defer-max rescale (T13)
    if (!__all(pm <= m + 8.0f)) {
      float mn = fmaxf(m, pm);
      float f = exp2f(m - mn);
      m = mn;
#pragma unroll
      for (int r = 0; r < 16; ++r) {
        float fr = __shfl(f, (r & 3) + 8 * (r >> 2) + 4 * hi);
        o0[r] *= fr; o1[r] *= fr; o2[r] *= fr;
      }
    }

    // exp (log2 domain; Q pre-scaled) + pack to bf16 pairs
    float pv0[16], pv1[16];
#pragma unroll
    for (int r = 0; r < 16; ++r) {
      pv0[r] = exp2f(sc0[r] - m);
      pv1[r] = exp2f(sc1[r] - m);
    }
    unsigned pk0[4][2], pk1[4][2];
#pragma unroll
    for (int q8 = 0; q8 < 4; ++q8)
#pragma unroll
      for (int i = 0; i < 2; ++i) {
        pk0[q8][i] = cvtpk_bf16(pv0[4 * q8 + 2 * i], pv0[4 * q8 + 2 * i + 1]);
        pk1[q8][i] = cvtpk_bf16(pv1[4 * q8 + 2 * i], pv1[4 * q8 + 2 * i + 1]);
      }

    // PV: assemble A-frags via permlane32_swap, B = V^T from Vl
#pragma unroll
    for (int kk = 0; kk < 4; ++kk) {
      const int e = (kk & 1) * 2;
      unsigned a0, a1, b0, b1;
      if (kk < 2) { a0 = pk0[e][0]; b0 = pk0[e + 1][0]; a1 = pk0[e][1]; b1 = pk0[e + 1][1]; }
      else        { a0 = pk1[e][0]; b0 = pk1[e + 1][0]; a1 = pk1[e][1]; b1 = pk1[e + 1][1]; }
      auto s0 = __builtin_amdgcn_permlane32_swap(a0, b0, false, false);
      auto s1 = __builtin_amdgcn_permlane32_swap(a1, b1, false, false);
      union { unsigned u[4]; s16x8 v; } fr_;
      fr_.u[0] = s0[0]; fr_.u[1] = s1[0]; fr_.u[2] = s0[1]; fr_.u[3] = s1[1];
      const int cb = ((2 * kk + hi) ^ (cq & 15)) << 3;
      s16x8 vf0 = *(const s16x8*)&Vl[cq * 128 + cb];
      s16x8 vf1 = *(const s16x8*)&Vl[(32 + cq) * 128 + cb];
      s16x8 vf2 = *(const s16x8*)&Vl[(64 + cq) * 128 + cb];
      o0 = mfma32(fr_.v, vf0, o0);
      o1 = mfma32(fr_.v, vf1, o1);
      o2 = mfma32(fr_.v, vf2, o2);
    }
  }

  // epilogue: l-sum lives in o2 at cq==16 (col 80)
#pragma unroll
  for (int r = 0; r < 16; ++r) {
    float lsum = __shfl(o2[r], 16 | (lane & 32));
    float inv = (lsum > 0.f) ? 1.f / lsum : 0.f;
    int srow = q0 + w * 32 + (r & 3) + 8 * (r >> 2) + 4 * hi;
    size_t base = (size_t)srow * EMB + h * HDIM;
    ctx[base + cq] = f2bf(o0[r] * inv);
    ctx[base + 32 + cq] = f2bf(o1[r] * inv);
    if (cq < 16) ctx[base + 64 + cq] = f2bf(o2[r] * inv);
  }
}

// ---------------- launch ----------------
extern "C" void kernel_launch(void* const* d_in, const int* in_sizes, int n_in,
                              void* d_out, int out_size, void* d_ws, size_t ws_size,
                              hipStream_t stream) {
  const float* x      = (const float*)d_in[0];
  const int*   cu     = (const int*)d_in[1];
  const float* rope   = (const float*)d_in[2];
  const float* w_qkv  = (const float*)d_in[3];
  const float* b_qkv  = (const float*)d_in[4];
  const float* w_proj = (const float*)d_in[5];
  const float* b_proj = (const float*)d_in[6];
  float* out = (float*)d_out;
  const int ncu = in_sizes[1];

  char* ws = (char*)d_ws;
  unsigned short* xb     = (unsigned short*)(ws + 0);          // 10485760 B
  unsigned short* wqkvb  = (unsigned short*)(ws + 10485760);   // 9830400 B
  unsigned short* wprojb = (unsigned short*)(ws + 20316160);   // 3276800 B
  float*          cosT   = (float*)(ws + 23592960);            // 655360 B
  float*          sinT   = (float*)(ws + 24248320);            // 655360 B
  unsigned short* qkvb   = (unsigned short*)(ws + 24903680);   // 31457280 B
  unsigned short* Qb     = (unsigned short*)(ws + 56360960);   // 10485760 B ([H][S][80])
  unsigned short* Kb     = (unsigned short*)(ws + 68943872);   // 10485760 B
  unsigned short* Vt     = (unsigned short*)(ws + 81526784);   // 10485760 B
  unsigned short* ctxb   = (unsigned short*)(ws + 92012544);   // 10485760 B

  cvt_kernel<<<5120, 256, 0, stream>>>(x, xb, 1310720);
  cvt_kernel<<<4800, 256, 0, stream>>>(w_qkv, wqkvb, 1228800);
  cvt_kernel<<<1600, 256, 0, stream>>>(w_proj, wprojb, 409600);
  rope_tab_kernel<<<640, 256, 0, stream>>>(rope, cosT, sinT, 163840);

  gemm256_kernel<1><<<dim3(15, 16), 512, 0, stream>>>(xb, wqkvb, b_qkv, (void*)qkvb,
                                                      4096, 3840, 1280);
  rope_split_kernel<<<dim3(64, 16), 256, 0, stream>>>(qkvb, cosT, sinT, Qb, Kb, Vt);
  attn_kernel<<<dim3(32, 16), 256, 0, stream>>>(Qb, Kb, Vt, cu, ncu, ctxb);
  gemm_kernel<0><<<dim3(10, 32), 256, 0, stream>>>(ctxb, wprojb, b_proj, (void*)out,
                                                   4096, 1280, 1280);
}

// Round 7
// 154.411 us; speedup vs baseline: 1.4850x; 1.0839x over previous
//
#include <hip/hip_runtime.h>
#include <hip/hip_bf16.h>
#include <stdint.h>
#include <stddef.h>

#define S_LEN 4096
#define EMB   1280
#define NH    16
#define HDIM  80
#define N3    3840
#define QSCALE 0.11180339887498949f   // 1/sqrt(80)
#define LOG2E  1.4426950408889634f

typedef __attribute__((ext_vector_type(4))) float f32x4;
typedef __attribute__((ext_vector_type(16))) float f32x16;
typedef __attribute__((ext_vector_type(4))) short s16x4;
typedef __attribute__((ext_vector_type(8))) short s16x8;
typedef __attribute__((ext_vector_type(8))) __bf16 bf16x8;

typedef __attribute__((address_space(1))) const unsigned int as1_u32;
typedef __attribute__((address_space(3))) unsigned int as3_u32;

__device__ __forceinline__ unsigned short f2bf(float f) {
  return __builtin_bit_cast(unsigned short, __float2bfloat16(f));
}
__device__ __forceinline__ float bf2f(unsigned short b) {
  union { unsigned int u; float f; } v; v.u = ((unsigned int)b) << 16;
  return v.f;
}

__device__ __forceinline__ f32x4 mfma16(s16x8 a, s16x8 b, f32x4 c) {
  return __builtin_amdgcn_mfma_f32_16x16x32_bf16(
      __builtin_bit_cast(bf16x8, a), __builtin_bit_cast(bf16x8, b), c, 0, 0, 0);
}
__device__ __forceinline__ f32x16 mfma32(s16x8 a, s16x8 b, f32x16 c) {
  return __builtin_amdgcn_mfma_f32_32x32x16_bf16(
      __builtin_bit_cast(bf16x8, a), __builtin_bit_cast(bf16x8, b), c, 0, 0, 0);
}

__device__ __forceinline__ unsigned cvtpk_bf16(float a, float b) {
  unsigned r;
  asm("v_cvt_pk_bf16_f32 %0, %1, %2" : "=v"(r) : "v"(a), "v"(b));
  return r;
}

__device__ __forceinline__ void gload16(const void* g, void* l) {
  __builtin_amdgcn_global_load_lds((as1_u32*)g, (as3_u32*)l, 16, 0, 0);
}

// ---------------- convert f32 -> bf16 (vectorized) ----------------
__global__ __launch_bounds__(256) void cvt_kernel(const float* __restrict__ in,
                                                  unsigned short* __restrict__ out, int n4) {
  int i = blockIdx.x * 256 + threadIdx.x;
  if (i >= n4) return;
  float4 v = ((const float4*)in)[i];
  s16x4 o;
  o[0] = (short)f2bf(v.x); o[1] = (short)f2bf(v.y);
  o[2] = (short)f2bf(v.z); o[3] = (short)f2bf(v.w);
  ((s16x4*)out)[i] = o;
}

// ---------------- cos/sin tables ----------------
__global__ __launch_bounds__(256) void rope_tab_kernel(const float* __restrict__ rope,
                                                       float* __restrict__ cosT,
                                                       float* __restrict__ sinT, int n) {
  int i = blockIdx.x * 256 + threadIdx.x;
  if (i >= n) return;
  float v = rope[i];
  float s, c;
  sincosf(v, &s, &c);
  cosT[i] = c; sinT[i] = s;
}

// ---------------- 256x256 bf16 GEMM, BK=64, deep pipeline, C = A * B^T + bias ----
// 512 threads = 8 waves (2M x 4N), per-wave C = 128x64. LDS 128KB (2 dbuf).
// Schedule per K-tile k (buf b=k&1):
//   vmcnt(8) ; barrier B1              <- stage(k) landed everywhere
//   ds_read 24 frags (kk=0,1)
//   MFMA kk=0 (32)                     <- overlaps other waves' ds_reads
//   lgkmcnt(0) ; barrier B2            <- all waves done reading buf b
//   issue stage(k+2) -> buf b          <- 2-K-tile prefetch distance
//   MFMA kk=1 (32)                     <- hides stage issue
// vmcnt never drains to 0 mid-loop (T4); setprio around MFMA clusters (T5).
// Chunk-XOR swizzle: phys_chunk = (kk*4+g) ^ (row&7); src-side inverse on the
// global address, LDS dest linear (global_load_lds contract, rule #21).
template<int BF16OUT>
__global__ __launch_bounds__(512, 2) void gemm256_kernel(const unsigned short* __restrict__ A,
                                                         const unsigned short* __restrict__ B,
                                                         const float* __restrict__ bias,
                                                         void* __restrict__ Cv,
                                                         int M, int N, int K,
                                                         int gx, int gy) {
  __shared__ __attribute__((aligned(16))) unsigned short lA[2][256 * 64];
  __shared__ __attribute__((aligned(16))) unsigned short lB[2][256 * 64];
  const int t = threadIdx.x;
  const int lane = t & 63, g = lane >> 4, c = lane & 15, cx = c & 7;
  const int w = t >> 6, wm = w >> 2, wn = w & 3;

  // bijective XCD swizzle (grid % 8 == 0 enforced by caller shapes)
  int nwg = gx * gy;
  int bid = blockIdx.x;
  int cpx = nwg >> 3;
  int swz = (bid & 7) * cpx + (bid >> 3);
  const int m0 = (swz / gx) * 256, n0 = (swz % gx) * 256;
  const int nt = K >> 6;

  // staging source addresses (hoisted; inverse-swizzled global chunk)
  const unsigned short* aS[4];
  const unsigned short* bS[4];
#pragma unroll
  for (int i = 0; i < 4; ++i) {
    int ch = t + i * 512;
    int row = ch >> 3, slot = ch & 7;
    int qsrc = slot ^ (row & 7);
    aS[i] = A + (size_t)(m0 + row) * K + qsrc * 8;
    bS[i] = B + (size_t)(n0 + row) * K + qsrc * 8;
  }

#define STAGE(buf, kt)                                      \
  do {                                                      \
    int _ko = (kt) * 64;                                    \
    gload16(aS[0] + _ko, &lA[buf][(t) * 8]);                \
    gload16(aS[1] + _ko, &lA[buf][(t + 512) * 8]);          \
    gload16(aS[2] + _ko, &lA[buf][(t + 1024) * 8]);         \
    gload16(aS[3] + _ko, &lA[buf][(t + 1536) * 8]);         \
    gload16(bS[0] + _ko, &lB[buf][(t) * 8]);                \
    gload16(bS[1] + _ko, &lB[buf][(t + 512) * 8]);          \
    gload16(bS[2] + _ko, &lB[buf][(t + 1024) * 8]);         \
    gload16(bS[3] + _ko, &lB[buf][(t + 1536) * 8]);         \
  } while (0)

  const f32x4 fz = {0.f, 0.f, 0.f, 0.f};
  f32x4 acc[8][4];
#pragma unroll
  for (int i = 0; i < 8; ++i)
#pragma unroll
    for (int j = 0; j < 4; ++j) acc[i][j] = fz;

  STAGE(0, 0);
  STAGE(1, 1);

  for (int k = 0; k < nt; ++k) {
    const int b = k & 1;
    if (k + 1 < nt) {
      asm volatile("s_waitcnt vmcnt(8)" ::: "memory");
    } else {
      asm volatile("s_waitcnt vmcnt(0)" ::: "memory");
    }
    __builtin_amdgcn_s_barrier();  // B1: buf b fully staged

    s16x8 af0[8], af1[8], bf0[4], bf1[4];
#pragma unroll
    for (int mf = 0; mf < 8; ++mf) {
      const unsigned short* rp = &lA[b][(wm * 128 + mf * 16 + c) * 64];
      af0[mf] = *(const s16x8*)(rp + (g ^ cx) * 8);
      af1[mf] = *(const s16x8*)(rp + ((4 ^ g ^ cx) * 8));
    }
#pragma unroll
    for (int nf = 0; nf < 4; ++nf) {
      const unsigned short* rp = &lB[b][(wn * 64 + nf * 16 + c) * 64];
      bf0[nf] = *(const s16x8*)(rp + (g ^ cx) * 8);
      bf1[nf] = *(const s16x8*)(rp + ((4 ^ g ^ cx) * 8));
    }

    __builtin_amdgcn_s_setprio(1);
#pragma unroll
    for (int mf = 0; mf < 8; ++mf)
#pragma unroll
      for (int nf = 0; nf < 4; ++nf)
        acc[mf][nf] = mfma16(af0[mf], bf0[nf], acc[mf][nf]);
    __builtin_amdgcn_s_setprio(0);

    asm volatile("s_waitcnt lgkmcnt(0)" ::: "memory");
    __builtin_amdgcn_sched_barrier(0);
    __builtin_amdgcn_s_barrier();  // B2: all waves done reading buf b

    if (k + 2 < nt) STAGE(b, k + 2);
    __builtin_amdgcn_sched_barrier(0);

    __builtin_amdgcn_s_setprio(1);
#pragma unroll
    for (int mf = 0; mf < 8; ++mf)
#pragma unroll
      for (int nf = 0; nf < 4; ++nf)
        acc[mf][nf] = mfma16(af1[mf], bf1[nf], acc[mf][nf]);
    __builtin_amdgcn_s_setprio(0);
  }
#undef STAGE

  const int ccol = n0 + wn * 64 + c;
  float bv[4];
#pragma unroll
  for (int nf = 0; nf < 4; ++nf) bv[nf] = bias[ccol + nf * 16];
#pragma unroll
  for (int mf = 0; mf < 8; ++mf)
#pragma unroll
    for (int r = 0; r < 4; ++r) {
      size_t rowoff = (size_t)(m0 + wm * 128 + mf * 16 + g * 4 + r) * N;
#pragma unroll
      for (int nf = 0; nf < 4; ++nf) {
        float vo = acc[mf][nf][r] + bv[nf];
        if (BF16OUT)
          ((unsigned short*)Cv)[rowoff + ccol + nf * 16] = f2bf(vo);
        else
          ((float*)Cv)[rowoff + ccol + nf * 16] = vo;
      }
    }
}

// ---------------- 128x128 bf16 GEMM (proj) ----------------
template<int BF16OUT>
__global__ __launch_bounds__(256) void gemm_kernel(const unsigned short* __restrict__ A,
                                                   const unsigned short* __restrict__ B,
                                                   const float* __restrict__ bias,
                                                   void* __restrict__ Cv,
                                                   int M, int N, int K) {
  __shared__ __attribute__((aligned(16))) unsigned short At[128 * 32];
  __shared__ __attribute__((aligned(16))) unsigned short Bt[128 * 32];
  const int t = threadIdx.x;
  const int lane = t & 63, g = lane >> 4, c = lane & 15;
  const int w = t >> 6, wm = w >> 1, wn = w & 1;
  const int m0 = blockIdx.y * 128, n0 = blockIdx.x * 128;

  const unsigned short* ag0 = A + (size_t)(m0 + (t >> 2)) * K + (t & 3) * 8;
  const unsigned short* ag1 = ag0 + (size_t)64 * K;
  const unsigned short* bg0 = B + (size_t)(n0 + (t >> 2)) * K + (t & 3) * 8;
  const unsigned short* bg1 = bg0 + (size_t)64 * K;
  unsigned short* al0 = &At[t * 8];
  unsigned short* al1 = &At[(t + 256) * 8];
  unsigned short* bl0 = &Bt[t * 8];
  unsigned short* bl1 = &Bt[(t + 256) * 8];

  const f32x4 fz = {0.f, 0.f, 0.f, 0.f};
  f32x4 acc[4][4];
#pragma unroll
  for (int i = 0; i < 4; ++i)
#pragma unroll
    for (int j = 0; j < 4; ++j) acc[i][j] = fz;

  for (int k0 = 0; k0 < K; k0 += 32) {
    __syncthreads();
    gload16(ag0 + k0, al0);
    gload16(ag1 + k0, al1);
    gload16(bg0 + k0, bl0);
    gload16(bg1 + k0, bl1);
    __syncthreads();
    s16x8 af[4], bf[4];
#pragma unroll
    for (int mf = 0; mf < 4; ++mf)
      af[mf] = *(const s16x8*)&At[(wm * 64 + mf * 16 + c) * 32 + g * 8];
#pragma unroll
    for (int nf = 0; nf < 4; ++nf)
      bf[nf] = *(const s16x8*)&Bt[(wn * 64 + nf * 16 + c) * 32 + g * 8];
#pragma unroll
    for (int mf = 0; mf < 4; ++mf)
#pragma unroll
      for (int nf = 0; nf < 4; ++nf)
        acc[mf][nf] = mfma16(af[mf], bf[nf], acc[mf][nf]);
  }

  const int crow = m0 + wm * 64 + g * 4;
  const int ccol = n0 + wn * 64 + c;
  float bv[4];
#pragma unroll
  for (int nf = 0; nf < 4; ++nf) bv[nf] = bias[ccol + nf * 16];
#pragma unroll
  for (int mf = 0; mf < 4; ++mf)
#pragma unroll
    for (int r = 0; r < 4; ++r) {
      size_t rowoff = (size_t)(crow + mf * 16 + r) * N;
#pragma unroll
      for (int nf = 0; nf < 4; ++nf) {
        float vo = acc[mf][nf][r] + bv[nf];
        if (BF16OUT)
          ((unsigned short*)Cv)[rowoff + ccol + nf * 16] = f2bf(vo);
        else
          ((float*)Cv)[rowoff + ccol + nf * 16] = vo;
      }
    }
}

// ---------------- RoPE + QKV split + V transpose ----------------
// qkv: [S][3840] bf16; Qb/Kb: [H][S][80] bf16 (Q pre-scaled by QSCALE*LOG2E);
// Vt: [H][80][S] bf16
__global__ __launch_bounds__(256) void rope_split_kernel(const unsigned short* __restrict__ qkv,
                                                         const float* __restrict__ cosT,
                                                         const float* __restrict__ sinT,
                                                         unsigned short* __restrict__ Qb,
                                                         unsigned short* __restrict__ Kb,
                                                         unsigned short* __restrict__ Vt) {
  __shared__ unsigned short vls[80][66];
  const int t = threadIdx.x;
  const int s0 = blockIdx.x * 64, h = blockIdx.y;

  for (int it = t; it < 64 * 10 * 2; it += 256) {
    int qk = it & 1;
    int jj = (it >> 1) % 10;
    int row = (it >> 1) / 10;
    int s = s0 + row;
    const unsigned short* src = qkv + (size_t)s * N3 + h * 240 + qk * 80;
    unsigned short* dst = (qk ? Kb : Qb) + ((size_t)h * S_LEN + s) * HDIM;
    int d0 = jj * 4;
    s16x4 a = *(const s16x4*)(src + d0);
    s16x4 b = *(const s16x4*)(src + 40 + d0);
    float4 cs = *(const float4*)(cosT + s * 40 + d0);
    float4 sn = *(const float4*)(sinT + s * 40 + d0);
    float sc = qk ? 1.f : (QSCALE * LOG2E);
    float ca[4] = {cs.x, cs.y, cs.z, cs.w};
    float sa[4] = {sn.x, sn.y, sn.z, sn.w};
    s16x4 o1, o2;
#pragma unroll
    for (int i = 0; i < 4; ++i) {
      float q1 = bf2f((unsigned short)a[i]);
      float q2 = bf2f((unsigned short)b[i]);
      o1[i] = (short)f2bf((q1 * ca[i] - q2 * sa[i]) * sc);
      o2[i] = (short)f2bf((q2 * ca[i] + q1 * sa[i]) * sc);
    }
    *(s16x4*)(dst + d0) = o1;
    *(s16x4*)(dst + 40 + d0) = o2;
  }

  for (int it = t; it < 640; it += 256) {
    int row = it / 10, c8 = it % 10;
    int s = s0 + row;
    s16x8 v = *(const s16x8*)(qkv + (size_t)s * N3 + h * 240 + 160 + c8 * 8);
#pragma unroll
    for (int i = 0; i < 8; ++i) vls[c8 * 8 + i][row] = (unsigned short)v[i];
  }
  __syncthreads();
  for (int it = t; it < 640; it += 256) {
    int d = it / 8, s8 = it % 8;
    s16x8 v;
#pragma unroll
    for (int i = 0; i < 8; ++i) v[i] = (short)vls[d][s8 * 8 + i];
    *(s16x8*)(Vt + ((size_t)h * HDIM + d) * S_LEN + s0 + s8 * 8) = v;
  }
}

// ---------------- flash attention, 32x32 swapped-QK^T, P-in-register ----------------
__global__ __launch_bounds__(256, 2) void attn_kernel(const unsigned short* __restrict__ Qb,
                                                      const unsigned short* __restrict__ Kb,
                                                      const unsigned short* __restrict__ Vt,
                                                      const int* __restrict__ cu, int ncu,
                                                      unsigned short* __restrict__ ctx) {
  __shared__ __attribute__((aligned(16))) unsigned short Kl[64 * 128];
  __shared__ __attribute__((aligned(16))) unsigned short Vl[96 * 128];
  const int t = threadIdx.x, lane = t & 63, w = t >> 6;
  const int cq = lane & 31, hi = lane >> 5;
  const int h = blockIdx.y, q0 = blockIdx.x * 128;
  const int nseg = ncu - 1;

  int qlo = 0, qhi = 0, ks = 0, ke = 0, wlo = 0, whi = 0, wlo2 = 0;
  const int myq = q0 + w * 32 + cq;
  const int wr0 = q0 + w * 32, wr1 = wr0 + 31;
  for (int i = 0; i < nseg; ++i) {
    int a = cu[i], b = cu[i + 1];
    if (myq >= a && myq < b) { qlo = a; qhi = b; }
    if (wr0 >= a && wr0 < b) { wlo = a; whi = b; }
    if (wr1 >= a && wr1 < b) { wlo2 = a; }
    if (q0 >= a && q0 < b) ks = a;
    if (q0 + 127 >= a && q0 + 127 < b) ke = b;
  }
  const bool uniform = (wlo == wlo2);
  const int k_begin = ks & ~63;

  s16x8 qf[5];
  {
    const unsigned short* qp = Qb + ((size_t)h * S_LEN + q0 + w * 32 + cq) * HDIM + hi * 8;
#pragma unroll
    for (int kk = 0; kk < 5; ++kk) qf[kk] = *(const s16x8*)(qp + kk * 16);
  }

  const unsigned short* kg = Kb + (size_t)h * S_LEN * HDIM;
  const unsigned short* vg = Vt + (size_t)h * HDIM * S_LEN;

  int kA[3], vA[3];
  const unsigned short* kgp[3];
  const unsigned short* vgp[3];
#pragma unroll
  for (int i = 0; i < 3; ++i) {
    int ch = t + i * 256;
    int chk = (ch < 640) ? ch : 0;
    int kr = chk & 63, kc = chk >> 6;
    kA[i] = kr * 128 + ((kc ^ (kr & 15)) << 3);
    kgp[i] = kg + (size_t)(k_begin + kr) * HDIM + kc * 8;
    int vd = chk % 80, vk = chk / 80;
    vA[i] = vd * 128 + ((vk ^ (vd & 15)) << 3);
    vgp[i] = vg + (size_t)vd * S_LEN + k_begin + vk * 8;
  }

  if (t < 128) {
    int d = 80 + (t >> 3), c8 = t & 7;
    unsigned short fv = (d == 80) ? (unsigned short)0x3F80 : (unsigned short)0;
    s16x8 vv;
#pragma unroll
    for (int i = 0; i < 8; ++i) vv[i] = (short)fv;
    *(s16x8*)&Vl[d * 128 + ((c8 ^ (d & 15)) << 3)] = vv;
  }

  const f32x16 z16 = {0.f,0.f,0.f,0.f,0.f,0.f,0.f,0.f,0.f,0.f,0.f,0.f,0.f,0.f,0.f,0.f};
  f32x16 o0 = z16, o1 = z16, o2 = z16;
  float m = -1e38f;

  s16x8 kreg[3], vreg[3];
  kreg[0] = *(const s16x8*)kgp[0];
  kreg[1] = *(const s16x8*)kgp[1];
  vreg[0] = *(const s16x8*)vgp[0];
  vreg[1] = *(const s16x8*)vgp[1];
  if (t < 128) { kreg[2] = *(const s16x8*)kgp[2]; vreg[2] = *(const s16x8*)vgp[2]; }

  for (int k0 = k_begin; k0 < ke; k0 += 64) {
    __syncthreads();
    *(s16x8*)&Kl[kA[0]] = kreg[0];
    *(s16x8*)&Kl[kA[1]] = kreg[1];
    *(s16x8*)&Vl[vA[0]] = vreg[0];
    *(s16x8*)&Vl[vA[1]] = vreg[1];
    if (t < 128) { *(s16x8*)&Kl[kA[2]] = kreg[2]; *(s16x8*)&Vl[vA[2]] = vreg[2]; }
    if (k0 + 64 < ke) {
#pragma unroll
      for (int i = 0; i < 3; ++i) { kgp[i] += 64 * HDIM; vgp[i] += 64; }
      kreg[0] = *(const s16x8*)kgp[0];
      kreg[1] = *(const s16x8*)kgp[1];
      vreg[0] = *(const s16x8*)vgp[0];
      vreg[1] = *(const s16x8*)vgp[1];
      if (t < 128) { kreg[2] = *(const s16x8*)kgp[2]; vreg[2] = *(const s16x8*)vgp[2]; }
    }
    __syncthreads();

    f32x16 sc0 = z16, sc1 = z16;
#pragma unroll
    for (int kk = 0; kk < 5; ++kk) {
      const int cb = ((2 * kk + hi) ^ (cq & 15)) << 3;
      s16x8 kf0 = *(const s16x8*)&Kl[cq * 128 + cb];
      s16x8 kf1 = *(const s16x8*)&Kl[(32 + cq) * 128 + cb];
      sc0 = mfma32(kf0, qf[kk], sc0);
      sc1 = mfma32(kf1, qf[kk], sc1);
    }

    if (!(uniform && k0 >= wlo && k0 + 64 <= whi)) {
#pragma unroll
      for (int r = 0; r < 16; ++r) {
        int key0 = k0 + (r & 3) + 8 * (r >> 2) + 4 * hi;
        int key1 = key0 + 32;
        sc0[r] = (key0 >= qlo && key0 < qhi) ? sc0[r] : -3e38f;
        sc1[r] = (key1 >= qlo && key1 < qhi) ? sc1[r] : -3e38f;
      }
    }

    float pm = fmaxf(sc0[0], sc1[0]);
#pragma unroll
    for (int r = 1; r < 16; ++r) pm = fmaxf(pm, fmaxf(sc0[r], sc1[r]));
    pm = fmaxf(pm, __shfl_xor(pm, 32));

    if (!__all(pm <= m + 8.0f)) {
      float mn = fmaxf(m, pm);
      float f = exp2f(m - mn);
      m = mn;
#pragma unroll
      for (int r = 0; r < 16; ++r) {
        float fr = __shfl(f, (r & 3) + 8 * (r >> 2) + 4 * hi);
        o0[r] *= fr; o1[r] *= fr; o2[r] *= fr;
      }
    }

    float pv0[16], pv1[16];
#pragma unroll
    for (int r = 0; r < 16; ++r) {
      pv0[r] = exp2f(sc0[r] - m);
      pv1[r] = exp2f(sc1[r] - m);
    }
    unsigned pk0[4][2], pk1[4][2];
#pragma unroll
    for (int q8 = 0; q8 < 4; ++q8)
#pragma unroll
      for (int i = 0; i < 2; ++i) {
        pk0[q8][i] = cvtpk_bf16(pv0[4 * q8 + 2 * i], pv0[4 * q8 + 2 * i + 1]);
        pk1[q8][i] = cvtpk_bf16(pv1[4 * q8 + 2 * i], pv1[4 * q8 + 2 * i + 1]);
      }

#pragma unroll
    for (int kk = 0; kk < 4; ++kk) {
      const int e = (kk & 1) * 2;
      unsigned a0, a1, b0, b1;
      if (kk < 2) { a0 = pk0[e][0]; b0 = pk0[e + 1][0]; a1 = pk0[e][1]; b1 = pk0[e + 1][1]; }
      else        { a0 = pk1[e][0]; b0 = pk1[e + 1][0]; a1 = pk1[e][1]; b1 = pk1[e + 1][1]; }
      auto s0 = __builtin_amdgcn_permlane32_swap(a0, b0, false, false);
      auto s1 = __builtin_amdgcn_permlane32_swap(a1, b1, false, false);
      union { unsigned u[4]; s16x8 v; } fr_;
      fr_.u[0] = s0[0]; fr_.u[1] = s1[0]; fr_.u[2] = s0[1]; fr_.u[3] = s1[1];
      const int cb = ((2 * kk + hi) ^ (cq & 15)) << 3;
      s16x8 vf0 = *(const s16x8*)&Vl[cq * 128 + cb];
      s16x8 vf1 = *(const s16x8*)&Vl[(32 + cq) * 128 + cb];
      s16x8 vf2 = *(const s16x8*)&Vl[(64 + cq) * 128 + cb];
      o0 = mfma32(fr_.v, vf0, o0);
      o1 = mfma32(fr_.v, vf1, o1);
      o2 = mfma32(fr_.v, vf2, o2);
    }
  }

#pragma unroll
  for (int r = 0; r < 16; ++r) {
    float lsum = __shfl(o2[r], 16 | (lane & 32));
    float inv = (lsum > 0.f) ? 1.f / lsum : 0.f;
    int srow = q0 + w * 32 + (r & 3) + 8 * (r >> 2) + 4 * hi;
    size_t base = (size_t)srow * EMB + h * HDIM;
    ctx[base + cq] = f2bf(o0[r] * inv);
    ctx[base + 32 + cq] = f2bf(o1[r] * inv);
    if (cq < 16) ctx[base + 64 + cq] = f2bf(o2[r] * inv);
  }
}

// ---------------- launch ----------------
extern "C" void kernel_launch(void* const* d_in, const int* in_sizes, int n_in,
                              void* d_out, int out_size, void* d_ws, size_t ws_size,
                              hipStream_t stream) {
  const float* x      = (const float*)d_in[0];
  const int*   cu     = (const int*)d_in[1];
  const float* rope   = (const float*)d_in[2];
  const float* w_qkv  = (const float*)d_in[3];
  const float* b_qkv  = (const float*)d_in[4];
  const float* w_proj = (const float*)d_in[5];
  const float* b_proj = (const float*)d_in[6];
  float* out = (float*)d_out;
  const int ncu = in_sizes[1];

  char* ws = (char*)d_ws;
  unsigned short* xb     = (unsigned short*)(ws + 0);          // 10485760 B
  unsigned short* wqkvb  = (unsigned short*)(ws + 10485760);   // 9830400 B
  unsigned short* wprojb = (unsigned short*)(ws + 20316160);   // 3276800 B
  float*          cosT   = (float*)(ws + 23592960);            // 655360 B
  float*          sinT   = (float*)(ws + 24248320);            // 655360 B
  unsigned short* qkvb   = (unsigned short*)(ws + 24903680);   // 31457280 B
  unsigned short* Qb     = (unsigned short*)(ws + 56360960);   // 10485760 B ([H][S][80])
  unsigned short* Kb     = (unsigned short*)(ws + 68943872);   // 10485760 B
  unsigned short* Vt     = (unsigned short*)(ws + 81526784);   // 10485760 B
  unsigned short* ctxb   = (unsigned short*)(ws + 92012544);   // 10485760 B

  cvt_kernel<<<5120, 256, 0, stream>>>(x, xb, 1310720);
  cvt_kernel<<<4800, 256, 0, stream>>>(w_qkv, wqkvb, 1228800);
  cvt_kernel<<<1600, 256, 0, stream>>>(w_proj, wprojb, 409600);
  rope_tab_kernel<<<640, 256, 0, stream>>>(rope, cosT, sinT, 163840);

  gemm256_kernel<1><<<240, 512, 0, stream>>>(xb, wqkvb, b_qkv, (void*)qkvb,
                                             4096, 3840, 1280, 15, 16);
  rope_split_kernel<<<dim3(64, 16), 256, 0, stream>>>(qkvb, cosT, sinT, Qb, Kb, Vt);
  attn_kernel<<<dim3(32, 16), 256, 0, stream>>>(Qb, Kb, Vt, cu, ncu, ctxb);
  gemm_kernel<0><<<dim3(10, 32), 256, 0, stream>>>(ctxb, wprojb, b_proj, (void*)out,
                                                   4096, 1280, 1280);
}

// Round 8
// 153.968 us; speedup vs baseline: 1.4893x; 1.0029x over previous
//
#include <hip/hip_runtime.h>
#include <hip/hip_bf16.h>
#include <stdint.h>
#include <stddef.h>

#define S_LEN 4096
#define EMB   1280
#define NH    16
#define HDIM  80
#define N3    3840
#define QSCALE 0.11180339887498949f   // 1/sqrt(80)
#define LOG2E  1.4426950408889634f

typedef __attribute__((ext_vector_type(4))) float f32x4;
typedef __attribute__((ext_vector_type(16))) float f32x16;
typedef __attribute__((ext_vector_type(4))) short s16x4;
typedef __attribute__((ext_vector_type(8))) short s16x8;
typedef __attribute__((ext_vector_type(8))) __bf16 bf16x8;

typedef __attribute__((address_space(1))) const unsigned int as1_u32;
typedef __attribute__((address_space(3))) unsigned int as3_u32;

__device__ __forceinline__ unsigned short f2bf(float f) {
  return __builtin_bit_cast(unsigned short, __float2bfloat16(f));
}
__device__ __forceinline__ float bf2f(unsigned short b) {
  union { unsigned int u; float f; } v; v.u = ((unsigned int)b) << 16;
  return v.f;
}

__device__ __forceinline__ f32x4 mfma16(s16x8 a, s16x8 b, f32x4 c) {
  return __builtin_amdgcn_mfma_f32_16x16x32_bf16(
      __builtin_bit_cast(bf16x8, a), __builtin_bit_cast(bf16x8, b), c, 0, 0, 0);
}
__device__ __forceinline__ f32x16 mfma32(s16x8 a, s16x8 b, f32x16 c) {
  return __builtin_amdgcn_mfma_f32_32x32x16_bf16(
      __builtin_bit_cast(bf16x8, a), __builtin_bit_cast(bf16x8, b), c, 0, 0, 0);
}

__device__ __forceinline__ unsigned cvtpk_bf16(float a, float b) {
  unsigned r;
  asm("v_cvt_pk_bf16_f32 %0, %1, %2" : "=v"(r) : "v"(a), "v"(b));
  return r;
}

__device__ __forceinline__ void gload16(const void* g, void* l) {
  __builtin_amdgcn_global_load_lds((as1_u32*)g, (as3_u32*)l, 16, 0, 0);
}

// ---------------- convert f32 -> bf16 (vectorized) ----------------
__global__ __launch_bounds__(256) void cvt_kernel(const float* __restrict__ in,
                                                  unsigned short* __restrict__ out, int n4) {
  int i = blockIdx.x * 256 + threadIdx.x;
  if (i >= n4) return;
  float4 v = ((const float4*)in)[i];
  s16x4 o;
  o[0] = (short)f2bf(v.x); o[1] = (short)f2bf(v.y);
  o[2] = (short)f2bf(v.z); o[3] = (short)f2bf(v.w);
  ((s16x4*)out)[i] = o;
}

// ---------------- cos/sin tables ----------------
__global__ __launch_bounds__(256) void rope_tab_kernel(const float* __restrict__ rope,
                                                       float* __restrict__ cosT,
                                                       float* __restrict__ sinT, int n) {
  int i = blockIdx.x * 256 + threadIdx.x;
  if (i >= n) return;
  float v = rope[i];
  float s, c;
  sincosf(v, &s, &c);
  cosT[i] = c; sinT[i] = s;
}

// ---------------- 256x256 bf16 GEMM, BK=64, deep pipeline, C = A * B^T + bias ----
template<int BF16OUT>
__global__ __launch_bounds__(512, 2) void gemm256_kernel(const unsigned short* __restrict__ A,
                                                         const unsigned short* __restrict__ B,
                                                         const float* __restrict__ bias,
                                                         void* __restrict__ Cv,
                                                         int M, int N, int K,
                                                         int gx, int gy) {
  __shared__ __attribute__((aligned(16))) unsigned short lA[2][256 * 64];
  __shared__ __attribute__((aligned(16))) unsigned short lB[2][256 * 64];
  const int t = threadIdx.x;
  const int lane = t & 63, g = lane >> 4, c = lane & 15, cx = c & 7;
  const int w = t >> 6, wm = w >> 2, wn = w & 3;

  int nwg = gx * gy;
  int bid = blockIdx.x;
  int cpx = nwg >> 3;
  int swz = (bid & 7) * cpx + (bid >> 3);
  const int m0 = (swz / gx) * 256, n0 = (swz % gx) * 256;
  const int nt = K >> 6;

  const unsigned short* aS[4];
  const unsigned short* bS[4];
#pragma unroll
  for (int i = 0; i < 4; ++i) {
    int ch = t + i * 512;
    int row = ch >> 3, slot = ch & 7;
    int qsrc = slot ^ (row & 7);
    aS[i] = A + (size_t)(m0 + row) * K + qsrc * 8;
    bS[i] = B + (size_t)(n0 + row) * K + qsrc * 8;
  }

#define STAGE(buf, kt)                                      \
  do {                                                      \
    int _ko = (kt) * 64;                                    \
    gload16(aS[0] + _ko, &lA[buf][(t) * 8]);                \
    gload16(aS[1] + _ko, &lA[buf][(t + 512) * 8]);          \
    gload16(aS[2] + _ko, &lA[buf][(t + 1024) * 8]);         \
    gload16(aS[3] + _ko, &lA[buf][(t + 1536) * 8]);         \
    gload16(bS[0] + _ko, &lB[buf][(t) * 8]);                \
    gload16(bS[1] + _ko, &lB[buf][(t + 512) * 8]);          \
    gload16(bS[2] + _ko, &lB[buf][(t + 1024) * 8]);         \
    gload16(bS[3] + _ko, &lB[buf][(t + 1536) * 8]);         \
  } while (0)

  const f32x4 fz = {0.f, 0.f, 0.f, 0.f};
  f32x4 acc[8][4];
#pragma unroll
  for (int i = 0; i < 8; ++i)
#pragma unroll
    for (int j = 0; j < 4; ++j) acc[i][j] = fz;

  STAGE(0, 0);
  STAGE(1, 1);

  for (int k = 0; k < nt; ++k) {
    const int b = k & 1;
    if (k + 1 < nt) {
      asm volatile("s_waitcnt vmcnt(8)" ::: "memory");
    } else {
      asm volatile("s_waitcnt vmcnt(0)" ::: "memory");
    }
    __builtin_amdgcn_s_barrier();  // B1: buf b fully staged

    s16x8 af0[8], af1[8], bf0[4], bf1[4];
#pragma unroll
    for (int mf = 0; mf < 8; ++mf) {
      const unsigned short* rp = &lA[b][(wm * 128 + mf * 16 + c) * 64];
      af0[mf] = *(const s16x8*)(rp + (g ^ cx) * 8);
      af1[mf] = *(const s16x8*)(rp + ((4 ^ g ^ cx) * 8));
    }
#pragma unroll
    for (int nf = 0; nf < 4; ++nf) {
      const unsigned short* rp = &lB[b][(wn * 64 + nf * 16 + c) * 64];
      bf0[nf] = *(const s16x8*)(rp + (g ^ cx) * 8);
      bf1[nf] = *(const s16x8*)(rp + ((4 ^ g ^ cx) * 8));
    }

    __builtin_amdgcn_s_setprio(1);
#pragma unroll
    for (int mf = 0; mf < 8; ++mf)
#pragma unroll
      for (int nf = 0; nf < 4; ++nf)
        acc[mf][nf] = mfma16(af0[mf], bf0[nf], acc[mf][nf]);
    __builtin_amdgcn_s_setprio(0);

    asm volatile("s_waitcnt lgkmcnt(0)" ::: "memory");
    __builtin_amdgcn_sched_barrier(0);
    __builtin_amdgcn_s_barrier();  // B2: all waves done reading buf b

    if (k + 2 < nt) STAGE(b, k + 2);
    __builtin_amdgcn_sched_barrier(0);

    __builtin_amdgcn_s_setprio(1);
#pragma unroll
    for (int mf = 0; mf < 8; ++mf)
#pragma unroll
      for (int nf = 0; nf < 4; ++nf)
        acc[mf][nf] = mfma16(af1[mf], bf1[nf], acc[mf][nf]);
    __builtin_amdgcn_s_setprio(0);
  }
#undef STAGE

  const int ccol = n0 + wn * 64 + c;
  float bv[4];
#pragma unroll
  for (int nf = 0; nf < 4; ++nf) bv[nf] = bias[ccol + nf * 16];
#pragma unroll
  for (int mf = 0; mf < 8; ++mf)
#pragma unroll
    for (int r = 0; r < 4; ++r) {
      size_t rowoff = (size_t)(m0 + wm * 128 + mf * 16 + g * 4 + r) * N;
#pragma unroll
      for (int nf = 0; nf < 4; ++nf) {
        float vo = acc[mf][nf][r] + bv[nf];
        if (BF16OUT)
          ((unsigned short*)Cv)[rowoff + ccol + nf * 16] = f2bf(vo);
        else
          ((float*)Cv)[rowoff + ccol + nf * 16] = vo;
      }
    }
}

// ---------------- 128x128 bf16 GEMM (proj) ----------------
template<int BF16OUT>
__global__ __launch_bounds__(256) void gemm_kernel(const unsigned short* __restrict__ A,
                                                   const unsigned short* __restrict__ B,
                                                   const float* __restrict__ bias,
                                                   void* __restrict__ Cv,
                                                   int M, int N, int K) {
  __shared__ __attribute__((aligned(16))) unsigned short At[128 * 32];
  __shared__ __attribute__((aligned(16))) unsigned short Bt[128 * 32];
  const int t = threadIdx.x;
  const int lane = t & 63, g = lane >> 4, c = lane & 15;
  const int w = t >> 6, wm = w >> 1, wn = w & 1;
  const int m0 = blockIdx.y * 128, n0 = blockIdx.x * 128;

  const unsigned short* ag0 = A + (size_t)(m0 + (t >> 2)) * K + (t & 3) * 8;
  const unsigned short* ag1 = ag0 + (size_t)64 * K;
  const unsigned short* bg0 = B + (size_t)(n0 + (t >> 2)) * K + (t & 3) * 8;
  const unsigned short* bg1 = bg0 + (size_t)64 * K;
  unsigned short* al0 = &At[t * 8];
  unsigned short* al1 = &At[(t + 256) * 8];
  unsigned short* bl0 = &Bt[t * 8];
  unsigned short* bl1 = &Bt[(t + 256) * 8];

  const f32x4 fz = {0.f, 0.f, 0.f, 0.f};
  f32x4 acc[4][4];
#pragma unroll
  for (int i = 0; i < 4; ++i)
#pragma unroll
    for (int j = 0; j < 4; ++j) acc[i][j] = fz;

  for (int k0 = 0; k0 < K; k0 += 32) {
    __syncthreads();
    gload16(ag0 + k0, al0);
    gload16(ag1 + k0, al1);
    gload16(bg0 + k0, bl0);
    gload16(bg1 + k0, bl1);
    __syncthreads();
    s16x8 af[4], bf[4];
#pragma unroll
    for (int mf = 0; mf < 4; ++mf)
      af[mf] = *(const s16x8*)&At[(wm * 64 + mf * 16 + c) * 32 + g * 8];
#pragma unroll
    for (int nf = 0; nf < 4; ++nf)
      bf[nf] = *(const s16x8*)&Bt[(wn * 64 + nf * 16 + c) * 32 + g * 8];
#pragma unroll
    for (int mf = 0; mf < 4; ++mf)
#pragma unroll
      for (int nf = 0; nf < 4; ++nf)
        acc[mf][nf] = mfma16(af[mf], bf[nf], acc[mf][nf]);
  }

  const int crow = m0 + wm * 64 + g * 4;
  const int ccol = n0 + wn * 64 + c;
  float bv[4];
#pragma unroll
  for (int nf = 0; nf < 4; ++nf) bv[nf] = bias[ccol + nf * 16];
#pragma unroll
  for (int mf = 0; mf < 4; ++mf)
#pragma unroll
    for (int r = 0; r < 4; ++r) {
      size_t rowoff = (size_t)(crow + mf * 16 + r) * N;
#pragma unroll
      for (int nf = 0; nf < 4; ++nf) {
        float vo = acc[mf][nf][r] + bv[nf];
        if (BF16OUT)
          ((unsigned short*)Cv)[rowoff + ccol + nf * 16] = f2bf(vo);
        else
          ((float*)Cv)[rowoff + ccol + nf * 16] = vo;
      }
    }
}

// ---------------- RoPE + QKV split + V transpose ----------------
// qkv: [S][3840] bf16; Qb/Kb: [H][S][80] bf16 (Q pre-scaled by QSCALE*LOG2E);
// Vt: [H][S/64][80][64] bf16 (TILED so attn's V-tile load is one contiguous 10KB block)
__global__ __launch_bounds__(256) void rope_split_kernel(const unsigned short* __restrict__ qkv,
                                                         const float* __restrict__ cosT,
                                                         const float* __restrict__ sinT,
                                                         unsigned short* __restrict__ Qb,
                                                         unsigned short* __restrict__ Kb,
                                                         unsigned short* __restrict__ Vt) {
  __shared__ unsigned short vls[80][66];
  const int t = threadIdx.x;
  const int s0 = blockIdx.x * 64, h = blockIdx.y;

  for (int it = t; it < 64 * 10 * 2; it += 256) {
    int qk = it & 1;
    int jj = (it >> 1) % 10;
    int row = (it >> 1) / 10;
    int s = s0 + row;
    const unsigned short* src = qkv + (size_t)s * N3 + h * 240 + qk * 80;
    unsigned short* dst = (qk ? Kb : Qb) + ((size_t)h * S_LEN + s) * HDIM;
    int d0 = jj * 4;
    s16x4 a = *(const s16x4*)(src + d0);
    s16x4 b = *(const s16x4*)(src + 40 + d0);
    float4 cs = *(const float4*)(cosT + s * 40 + d0);
    float4 sn = *(const float4*)(sinT + s * 40 + d0);
    float sc = qk ? 1.f : (QSCALE * LOG2E);
    float ca[4] = {cs.x, cs.y, cs.z, cs.w};
    float sa[4] = {sn.x, sn.y, sn.z, sn.w};
    s16x4 o1, o2;
#pragma unroll
    for (int i = 0; i < 4; ++i) {
      float q1 = bf2f((unsigned short)a[i]);
      float q2 = bf2f((unsigned short)b[i]);
      o1[i] = (short)f2bf((q1 * ca[i] - q2 * sa[i]) * sc);
      o2[i] = (short)f2bf((q2 * ca[i] + q1 * sa[i]) * sc);
    }
    *(s16x4*)(dst + d0) = o1;
    *(s16x4*)(dst + 40 + d0) = o2;
  }

  for (int it = t; it < 640; it += 256) {
    int row = it / 10, c8 = it % 10;
    int s = s0 + row;
    s16x8 v = *(const s16x8*)(qkv + (size_t)s * N3 + h * 240 + 160 + c8 * 8);
#pragma unroll
    for (int i = 0; i < 8; ++i) vls[c8 * 8 + i][row] = (unsigned short)v[i];
  }
  __syncthreads();
  for (int it = t; it < 640; it += 256) {
    int d = it / 8, s8 = it % 8;
    s16x8 v;
#pragma unroll
    for (int i = 0; i < 8; ++i) v[i] = (short)vls[d][s8 * 8 + i];
    *(s16x8*)(Vt + (((size_t)h * 64 + (s0 >> 6)) * 80 + d) * 64 + s8 * 8) = v;
  }
}

// ---------------- flash attention, 32x32 swapped-QK^T, P-in-register ----------------
// Coalesced staging: K-tile = contiguous 10KB of [S][80]; V-tile = contiguous
// 10KB block of the tiled Vt layout. Chunk ch (16B) -> global off ch*16B linear.
__global__ __launch_bounds__(256, 2) void attn_kernel(const unsigned short* __restrict__ Qb,
                                                      const unsigned short* __restrict__ Kb,
                                                      const unsigned short* __restrict__ Vt,
                                                      const int* __restrict__ cu, int ncu,
                                                      unsigned short* __restrict__ ctx) {
  __shared__ __attribute__((aligned(16))) unsigned short Kl[64 * 128];
  __shared__ __attribute__((aligned(16))) unsigned short Vl[96 * 128];
  const int t = threadIdx.x, lane = t & 63, w = t >> 6;
  const int cq = lane & 31, hi = lane >> 5;
  const int h = blockIdx.y, q0 = blockIdx.x * 128;
  const int nseg = ncu - 1;

  int qlo = 0, qhi = 0, ks = 0, ke = 0, wlo = 0, whi = 0, wlo2 = 0;
  const int myq = q0 + w * 32 + cq;
  const int wr0 = q0 + w * 32, wr1 = wr0 + 31;
  for (int i = 0; i < nseg; ++i) {
    int a = cu[i], b = cu[i + 1];
    if (myq >= a && myq < b) { qlo = a; qhi = b; }
    if (wr0 >= a && wr0 < b) { wlo = a; whi = b; }
    if (wr1 >= a && wr1 < b) { wlo2 = a; }
    if (q0 >= a && q0 < b) ks = a;
    if (q0 + 127 >= a && q0 + 127 < b) ke = b;
  }
  const bool uniform = (wlo == wlo2);
  const int k_begin = ks & ~63;

  s16x8 qf[5];
  {
    const unsigned short* qp = Qb + ((size_t)h * S_LEN + q0 + w * 32 + cq) * HDIM + hi * 8;
#pragma unroll
    for (int kk = 0; kk < 5; ++kk) qf[kk] = *(const s16x8*)(qp + kk * 16);
  }

  // linear-chunk staging: K tile base = Kb + h*S*80 + k0*80 ; V tile base =
  // Vt + ((h*64 + k0/64)*80)*64. Both advance by 5120 ushorts per tile.
  int kA[3], vA[3];
  const unsigned short* kgp[3];
  const unsigned short* vgp[3];
  {
    const unsigned short* kbase = Kb + (size_t)h * S_LEN * HDIM + (size_t)k_begin * HDIM;
    const unsigned short* vbase = Vt + ((size_t)h * 64 + (k_begin >> 6)) * 5120;
#pragma unroll
    for (int i = 0; i < 3; ++i) {
      int ch = t + i * 256;
      int chk = (ch < 640) ? ch : 0;
      int kr = chk / 10, kc = chk % 10;
      kA[i] = kr * 128 + ((kc ^ (kr & 15)) << 3);
      kgp[i] = kbase + chk * 8;
      int vd = chk >> 3, vk = chk & 7;
      vA[i] = vd * 128 + ((vk ^ (vd & 15)) << 3);
      vgp[i] = vbase + chk * 8;
    }
  }

  if (t < 128) {
    int d = 80 + (t >> 3), c8 = t & 7;
    unsigned short fv = (d == 80) ? (unsigned short)0x3F80 : (unsigned short)0;
    s16x8 vv;
#pragma unroll
    for (int i = 0; i < 8; ++i) vv[i] = (short)fv;
    *(s16x8*)&Vl[d * 128 + ((c8 ^ (d & 15)) << 3)] = vv;
  }

  const f32x16 z16 = {0.f,0.f,0.f,0.f,0.f,0.f,0.f,0.f,0.f,0.f,0.f,0.f,0.f,0.f,0.f,0.f};
  f32x16 o0 = z16, o1 = z16, o2 = z16;
  float m = -1e38f;

  s16x8 kreg[3], vreg[3];
  kreg[0] = *(const s16x8*)kgp[0];
  kreg[1] = *(const s16x8*)kgp[1];
  vreg[0] = *(const s16x8*)vgp[0];
  vreg[1] = *(const s16x8*)vgp[1];
  if (t < 128) { kreg[2] = *(const s16x8*)kgp[2]; vreg[2] = *(const s16x8*)vgp[2]; }

  for (int k0 = k_begin; k0 < ke; k0 += 64) {
    __syncthreads();
    *(s16x8*)&Kl[kA[0]] = kreg[0];
    *(s16x8*)&Kl[kA[1]] = kreg[1];
    *(s16x8*)&Vl[vA[0]] = vreg[0];
    *(s16x8*)&Vl[vA[1]] = vreg[1];
    if (t < 128) { *(s16x8*)&Kl[kA[2]] = kreg[2]; *(s16x8*)&Vl[vA[2]] = vreg[2]; }
    if (k0 + 64 < ke) {
#pragma unroll
      for (int i = 0; i < 3; ++i) { kgp[i] += 5120; vgp[i] += 5120; }
      kreg[0] = *(const s16x8*)kgp[0];
      kreg[1] = *(const s16x8*)kgp[1];
      vreg[0] = *(const s16x8*)vgp[0];
      vreg[1] = *(const s16x8*)vgp[1];
      if (t < 128) { kreg[2] = *(const s16x8*)kgp[2]; vreg[2] = *(const s16x8*)vgp[2]; }
    }
    __syncthreads();

    f32x16 sc0 = z16, sc1 = z16;
#pragma unroll
    for (int kk = 0; kk < 5; ++kk) {
      const int cb = ((2 * kk + hi) ^ (cq & 15)) << 3;
      s16x8 kf0 = *(const s16x8*)&Kl[cq * 128 + cb];
      s16x8 kf1 = *(const s16x8*)&Kl[(32 + cq) * 128 + cb];
      sc0 = mfma32(kf0, qf[kk], sc0);
      sc1 = mfma32(kf1, qf[kk], sc1);
    }

    if (!(uniform && k0 >= wlo && k0 + 64 <= whi)) {
#pragma unroll
      for (int r = 0; r < 16; ++r) {
        int key0 = k0 + (r & 3) + 8 * (r >> 2) + 4 * hi;
        int key1 = key0 + 32;
        sc0[r] = (key0 >= qlo && key0 < qhi) ? sc0[r] : -3e38f;
        sc1[r] = (key1 >= qlo && key1 < qhi) ? sc1[r] : -3e38f;
      }
    }

    float pm = fmaxf(sc0[0], sc1[0]);
#pragma unroll
    for (int r = 1; r < 16; ++r) pm = fmaxf(pm, fmaxf(sc0[r], sc1[r]));
    pm = fmaxf(pm, __shfl_xor(pm, 32));

    if (!__all(pm <= m + 8.0f)) {
      float mn = fmaxf(m, pm);
      float f = exp2f(m - mn);
      m = mn;
#pragma unroll
      for (int r = 0; r < 16; ++r) {
        float fr = __shfl(f, (r & 3) + 8 * (r >> 2) + 4 * hi);
        o0[r] *= fr; o1[r] *= fr; o2[r] *= fr;
      }
    }

    float pv0[16], pv1[16];
#pragma unroll
    for (int r = 0; r < 16; ++r) {
      pv0[r] = exp2f(sc0[r] - m);
      pv1[r] = exp2f(sc1[r] - m);
    }
    unsigned pk0[4][2], pk1[4][2];
#pragma unroll
    for (int q8 = 0; q8 < 4; ++q8)
#pragma unroll
      for (int i = 0; i < 2; ++i) {
        pk0[q8][i] = cvtpk_bf16(pv0[4 * q8 + 2 * i], pv0[4 * q8 + 2 * i + 1]);
        pk1[q8][i] = cvtpk_bf16(pv1[4 * q8 + 2 * i], pv1[4 * q8 + 2 * i + 1]);
      }

#pragma unroll
    for (int kk = 0; kk < 4; ++kk) {
      const int e = (kk & 1) * 2;
      unsigned a0, a1, b0, b1;
      if (kk < 2) { a0 = pk0[e][0]; b0 = pk0[e + 1][0]; a1 = pk0[e][1]; b1 = pk0[e + 1][1]; }
      else        { a0 = pk1[e][0]; b0 = pk1[e + 1][0]; a1 = pk1[e][1]; b1 = pk1[e + 1][1]; }
      auto s0 = __builtin_amdgcn_permlane32_swap(a0, b0, false, false);
      auto s1 = __builtin_amdgcn_permlane32_swap(a1, b1, false, false);
      union { unsigned u[4]; s16x8 v; } fr_;
      fr_.u[0] = s0[0]; fr_.u[1] = s1[0]; fr_.u[2] = s0[1]; fr_.u[3] = s1[1];
      const int cb = ((2 * kk + hi) ^ (cq & 15)) << 3;
      s16x8 vf0 = *(const s16x8*)&Vl[cq * 128 + cb];
      s16x8 vf1 = *(const s16x8*)&Vl[(32 + cq) * 128 + cb];
      s16x8 vf2 = *(const s16x8*)&Vl[(64 + cq) * 128 + cb];
      o0 = mfma32(fr_.v, vf0, o0);
      o1 = mfma32(fr_.v, vf1, o1);
      o2 = mfma32(fr_.v, vf2, o2);
    }
  }

#pragma unroll
  for (int r = 0; r < 16; ++r) {
    float lsum = __shfl(o2[r], 16 | (lane & 32));
    float inv = (lsum > 0.f) ? 1.f / lsum : 0.f;
    int srow = q0 + w * 32 + (r & 3) + 8 * (r >> 2) + 4 * hi;
    size_t base = (size_t)srow * EMB + h * HDIM;
    ctx[base + cq] = f2bf(o0[r] * inv);
    ctx[base + 32 + cq] = f2bf(o1[r] * inv);
    if (cq < 16) ctx[base + 64 + cq] = f2bf(o2[r] * inv);
  }
}

// ---------------- launch ----------------
extern "C" void kernel_launch(void* const* d_in, const int* in_sizes, int n_in,
                              void* d_out, int out_size, void* d_ws, size_t ws_size,
                              hipStream_t stream) {
  const float* x      = (const float*)d_in[0];
  const int*   cu     = (const int*)d_in[1];
  const float* rope   = (const float*)d_in[2];
  const float* w_qkv  = (const float*)d_in[3];
  const float* b_qkv  = (const float*)d_in[4];
  const float* w_proj = (const float*)d_in[5];
  const float* b_proj = (const float*)d_in[6];
  float* out = (float*)d_out;
  const int ncu = in_sizes[1];

  char* ws = (char*)d_ws;
  unsigned short* xb     = (unsigned short*)(ws + 0);          // 10485760 B
  unsigned short* wqkvb  = (unsigned short*)(ws + 10485760);   // 9830400 B
  unsigned short* wprojb = (unsigned short*)(ws + 20316160);   // 3276800 B
  float*          cosT   = (float*)(ws + 23592960);            // 655360 B
  float*          sinT   = (float*)(ws + 24248320);            // 655360 B
  unsigned short* qkvb   = (unsigned short*)(ws + 24903680);   // 31457280 B
  unsigned short* Qb     = (unsigned short*)(ws + 56360960);   // 10485760 B ([H][S][80])
  unsigned short* Kb     = (unsigned short*)(ws + 68943872);   // 10485760 B
  unsigned short* Vt     = (unsigned short*)(ws + 81526784);   // 10485760 B (tiled)
  unsigned short* ctxb   = (unsigned short*)(ws + 92012544);   // 10485760 B

  cvt_kernel<<<5120, 256, 0, stream>>>(x, xb, 1310720);
  cvt_kernel<<<4800, 256, 0, stream>>>(w_qkv, wqkvb, 1228800);
  cvt_kernel<<<1600, 256, 0, stream>>>(w_proj, wprojb, 409600);
  rope_tab_kernel<<<640, 256, 0, stream>>>(rope, cosT, sinT, 163840);

  gemm256_kernel<1><<<240, 512, 0, stream>>>(xb, wqkvb, b_qkv, (void*)qkvb,
                                             4096, 3840, 1280, 15, 16);
  rope_split_kernel<<<dim3(64, 16), 256, 0, stream>>>(qkvb, cosT, sinT, Qb, Kb, Vt);
  attn_kernel<<<dim3(32, 16), 256, 0, stream>>>(Qb, Kb, Vt, cu, ncu, ctxb);
  gemm_kernel<0><<<dim3(10, 32), 256, 0, stream>>>(ctxb, wprojb, b_proj, (void*)out,
                                                   4096, 1280, 1280);
}